// Round 11
// baseline (200.143 us; speedup 1.0000x reference)
//
#include <hip/hip_runtime.h>
#include <hip/hip_bf16.h>

// GCNConv: out[i] = sum_{e: row[e]=i} dis[row]*dis[col]*xl[col] + dis[i]^2*xl[i]
// N=50000, E=1.6M, D=128, fp32 in/out.
//
// R10 -> R11: k_reduce (51us) co-limited: 45% VALU, 45% L2-fill (FETCH 155MB).
//  - k_split key -> (rowlocal, col>>12): per-node neighbor lists ordered by
//    col-band; concurrent waves sweep col-space in-phase -> L2-resident band.
//  - k_reduce: half-wave-per-edge (lane covers 4 features, uint2 loads):
//    1 shfl + 0.5 load-instr per edge instead of 2 + 1.
//  - k_init+k_prepw merged.

#define D     128
#define TILE  8192
#define BINB  1024      // k_bin block size
#define RPB   256       // rows per bucket
#define MAXB  256       // bucket id must fit 8 bits
#define SPLIT_CAP 16384 // LDS sort capacity (= CAP for N=50000/E=1.6M)
#define CSEG  16        // col-bands per node for sweep locality
#define DSEG  4         // degree histogram segments
#define DTIL  32        // degree histogram tiles over E

typedef short  bf16x8 __attribute__((ext_vector_type(8)));
typedef float  f32x4  __attribute__((ext_vector_type(4)));
typedef unsigned short us4 __attribute__((ext_vector_type(4)));
typedef unsigned short us8 __attribute__((ext_vector_type(8)));

static __device__ __forceinline__ unsigned short f2bf(float f) {
    unsigned u = __float_as_uint(f);
    u = (u + 0x7FFFu + ((u >> 16) & 1u)) >> 16;   // RNE
    return (unsigned short)u;
}
static __device__ __forceinline__ float bf2f(unsigned short s) {
    return __uint_as_float(((unsigned)s) << 16);
}

// --- init: cntc=0, bcur[b]=b*CAP, wtb = bf16(W^T) ------------------------
__global__ __launch_bounds__(256) void k_prep(const float* __restrict__ W,
                                              unsigned short* __restrict__ wtb,
                                              int* __restrict__ cntc,
                                              int* __restrict__ bcur,
                                              int N, int NB, int CAP) {
    int i = blockIdx.x * 256 + threadIdx.x;
    if (i < N) cntc[i] = 0;
    if (i < NB) bcur[i] = i * CAP;
    if (i < D * D) {
        int n = i >> 7, k = i & 127;
        wtb[n * 128 + k] = f2bf(W[k * 128 + n]);
    }
}

// --- single-pass bin into fixed-stride bucket regions --------------------
__global__ __launch_bounds__(BINB) void k_bin(const int* __restrict__ rows,
                                              const int* __restrict__ cols,
                                              int* __restrict__ bcur,
                                              unsigned* __restrict__ ebuf,
                                              int E, int NB, int CAP) {
    __shared__ int lcnt[MAXB];
    __shared__ int lbase[MAXB];
    const int t = threadIdx.x;
    const int base = blockIdx.x * TILE;
    int m = E - base; if (m > TILE) m = TILE;

    unsigned p[TILE / BINB];
    #pragma unroll
    for (int it = 0; it < TILE / BINB; ++it) {
        int i = it * BINB + t;
        if (i < m) {
            unsigned r = (unsigned)rows[base + i];
            unsigned c = (unsigned)cols[base + i];
            p[it] = c | ((r & 255u) << 16) | ((r >> 8) << 24);
        }
    }
    for (int b = t; b < NB; b += BINB) lcnt[b] = 0;
    __syncthreads();
    #pragma unroll
    for (int it = 0; it < TILE / BINB; ++it) {
        int i = it * BINB + t;
        if (i < m) atomicAdd(&lcnt[p[it] >> 24], 1);
    }
    __syncthreads();
    for (int b = t; b < NB; b += BINB) {
        int c = lcnt[b];
        lbase[b] = c ? atomicAdd(&bcur[b], c) : 0;
        lcnt[b] = 0;
    }
    __syncthreads();
    #pragma unroll
    for (int it = 0; it < TILE / BINB; ++it) {
        int i = it * BINB + t;
        if (i < m) {
            int bk = p[it] >> 24;
            int r  = atomicAdd(&lcnt[bk], 1);
            int pos = lbase[bk] + r;
            if (pos < (bk + 1) * CAP)               // overflow guard (never fires)
                ebuf[pos] = p[it] & 0xFFFFFFu;      // col | rowlocal<<16
        }
    }
}

// --- degree: segmented LDS histogram (no random global atomics) ----------
__global__ __launch_bounds__(1024) void k_deg2(const int* __restrict__ cols,
                                               int* __restrict__ cntc,
                                               int E, int N) {
    const int segw = (N + DSEG - 1) / DSEG;         // 12500
    __shared__ int h[12544];                        // >= segw
    const int seg  = blockIdx.x & (DSEG - 1);
    const int tile = blockIdx.x >> 2;               // DSEG==4
    const int lo = seg * segw;
    const int hi = min(lo + segw, N);
    const int w  = hi - lo;
    for (int i = threadIdx.x; i < w; i += 1024) h[i] = 0;
    __syncthreads();
    const int per = (E + DTIL - 1) / DTIL;
    const int beg = tile * per;
    const int end = min(beg + per, E);
    for (int i = beg + threadIdx.x; i < end; i += 1024) {
        int c = cols[i];
        if (c >= lo && c < hi) atomicAdd(&h[c - lo], 1);
    }
    __syncthreads();
    for (int i = threadIdx.x; i < w; i += 1024) {
        int v = h[i];
        if (v) atomicAdd(&cntc[lo + i], v);         // coalesced merge
    }
}

// --- dis = rsqrt(deg_col + 1) --------------------------------------------
__global__ __launch_bounds__(256) void k_dis(const int* __restrict__ cntc,
                                             float* __restrict__ dis, int N) {
    int i = blockIdx.x * 256 + threadIdx.x;
    if (i < N) dis[i] = rsqrtf((float)(cntc[i] + 1));
}

// --- per-bucket counting sort in LDS, key=(rowlocal, col-band) -----------
__global__ __launch_bounds__(1024) void k_split(const int* __restrict__ bcur,
                                                const unsigned* __restrict__ ebuf,
                                                unsigned short* __restrict__ ecol,
                                                int* __restrict__ begN,
                                                int* __restrict__ endN,
                                                int N, int CAP, int colshift) {
    __shared__ unsigned short sorted[SPLIT_CAP];    // 32 KB
    __shared__ int cnt[RPB * CSEG];                 // 4096 keys, 16 KB
    __shared__ int psum[1024];
    const int b = blockIdx.x, t = threadIdx.x;
    const int base = b * CAP;
    int m = bcur[b] - base; if (m > CAP) m = CAP;
    #pragma unroll
    for (int u = 0; u < 4; ++u) cnt[u * 1024 + t] = 0;
    __syncthreads();
    for (int i = t; i < m; i += 1024) {
        unsigned p = ebuf[base + i];
        int key = (int)((p >> 16) & 255) * CSEG + (int)((p & 0xFFFFu) >> colshift);
        atomicAdd(&cnt[key], 1);
    }
    __syncthreads();
    // parallel exclusive scan of 4096 (4 per thread + 1024-ladder)
    int a0 = cnt[4 * t], a1 = cnt[4 * t + 1], a2 = cnt[4 * t + 2], a3 = cnt[4 * t + 3];
    int tot = a0 + a1 + a2 + a3;
    psum[t] = tot;
    __syncthreads();
    for (int off = 1; off < 1024; off <<= 1) {
        int add = (t >= off) ? psum[t - off] : 0;
        __syncthreads();
        psum[t] += add;
        __syncthreads();
    }
    int ex = psum[t] - tot;
    cnt[4 * t]     = ex;
    cnt[4 * t + 1] = ex + a0;
    cnt[4 * t + 2] = ex + a0 + a1;
    cnt[4 * t + 3] = ex + a0 + a1 + a2;
    __syncthreads();
    // per-node ranges from key-boundaries (before cursor mutation)
    const int row0 = b * RPB;
    if (t < RPB && row0 + t < N) {
        begN[row0 + t] = base + cnt[t * CSEG];
        endN[row0 + t] = base + ((t == RPB - 1) ? m : cnt[(t + 1) * CSEG]);
    }
    __syncthreads();
    // scatter into LDS (cnt doubles as cursor)
    for (int i = t; i < m; i += 1024) {
        unsigned p = ebuf[base + i];
        int key = (int)((p >> 16) & 255) * CSEG + (int)((p & 0xFFFFu) >> colshift);
        int pos = atomicAdd(&cnt[key], 1);
        sorted[pos] = (unsigned short)(p & 0xFFFFu);
    }
    __syncthreads();
    for (int i = t; i < m; i += 1024)
        ecol[base + i] = sorted[i];                 // linear coalesced write
}

// --- MFMA bf16 GEMM: xlb = bf16(x @ W + b), 64x128 tile per block --------
__global__ __launch_bounds__(256) void k_gemm(const float* __restrict__ x,
                                              const unsigned short* __restrict__ wtb,
                                              const float* __restrict__ bia,
                                              unsigned short* __restrict__ xlb,
                                              int N) {
    __shared__ unsigned short wt[128][136];   // W^T bf16, pad 8 -> 16B-aligned rows
    __shared__ unsigned short xs[64][136];    // x tile bf16
    const int t = threadIdx.x;
    const int row0 = blockIdx.x * 64;

    #pragma unroll
    for (int i = 0; i < 8; ++i) {             // W^T: 2048 ushort8, ds_write_b128
        int j = i * 256 + t;
        int n = j >> 4, k8 = j & 15;
        us8 v = *(const us8*)&wtb[j * 8];
        *(us8*)&wt[n][k8 * 8] = v;
    }
    #pragma unroll
    for (int i = 0; i < 8; ++i) {             // x: 2048 float4 -> ushort4
        int j = i * 256 + t;
        int r = j >> 5, c4 = j & 31;
        int gr = row0 + r;
        us4 o = (us4){0, 0, 0, 0};
        if (gr < N) {
            float4 v = *(const float4*)&x[(size_t)gr * D + c4 * 4];
            o = (us4){f2bf(v.x), f2bf(v.y), f2bf(v.z), f2bf(v.w)};
        }
        *(us4*)&xs[r][c4 * 4] = o;
    }
    __syncthreads();

    const int w  = t >> 6, l = t & 63;
    const int m0 = w * 16;
    const int lm = l & 15, lq = l >> 4;

    f32x4 acc[8];
    #pragma unroll
    for (int nt = 0; nt < 8; ++nt) acc[nt] = (f32x4){0.f, 0.f, 0.f, 0.f};

    #pragma unroll
    for (int kk = 0; kk < 4; ++kk) {
        const int kof = kk * 32 + lq * 8;
        bf16x8 a = *(const bf16x8*)&xs[m0 + lm][kof];
        #pragma unroll
        for (int nt = 0; nt < 8; ++nt) {
            bf16x8 bb = *(const bf16x8*)&wt[nt * 16 + lm][kof];
            acc[nt] = __builtin_amdgcn_mfma_f32_16x16x32_bf16(a, bb, acc[nt], 0, 0, 0);
        }
    }

    #pragma unroll
    for (int nt = 0; nt < 8; ++nt) {
        const int col = nt * 16 + lm;
        const float bc = bia[col];
        #pragma unroll
        for (int r = 0; r < 4; ++r) {
            int grow = row0 + m0 + lq * 4 + r;
            if (grow < N) xlb[(size_t)grow * D + col] = f2bf(acc[nt][r] + bc);
        }
    }
}

// --- wave-per-node gather-reduce, half-wave per edge ---------------------
__global__ __launch_bounds__(256) void k_reduce(const int* __restrict__ begN,
                                                const int* __restrict__ endN,
                                                const unsigned short* __restrict__ ecol,
                                                const float* __restrict__ dis,
                                                const unsigned short* __restrict__ xlb,
                                                float* __restrict__ out, int N) {
    const int wave = threadIdx.x >> 6;
    const int lane = threadIdx.x & 63;
    const int half = lane >> 5;          // 0 or 1: which edge of a pair
    const int hl   = lane & 31;          // lane in half; features [4hl, 4hl+3]
    const int i = blockIdx.x * 4 + wave;
    if (i >= N) return;
    const float di = dis[i];

    float a0 = 0.f, a1 = 0.f, a2 = 0.f, a3 = 0.f;
    if (half == 0) {                     // self loop into half 0
        uint2 s = *(const uint2*)(xlb + (size_t)i * D + hl * 4);
        float w = di * di;
        a0 = w * __uint_as_float(s.x << 16);
        a1 = w * __uint_as_float(s.x & 0xFFFF0000u);
        a2 = w * __uint_as_float(s.y << 16);
        a3 = w * __uint_as_float(s.y & 0xFFFF0000u);
    }

    const int beg = begN[i], end = endN[i];
    for (int base = beg; base < end; base += 64) {
        int m = end - base; if (m > 64) m = 64;
        int c = 0; float n = 0.f;
        if (lane < m) {                  // stage 64 edges across the wave
            c = ecol[base + lane];
            n = di * dis[c];
        }
        for (int j = 0; j < m; j += 16) {            // 16 edges, 8-deep MLP
            uint2 dv[8]; float nn[8];
            #pragma unroll
            for (int u = 0; u < 8; ++u) {
                int slot = j + 2 * u + half;         // halves split the pair
                int cc = __shfl(c, slot);            // slots >= m carry c=0,n=0
                nn[u] = __shfl(n, slot);
                dv[u] = *(const uint2*)(xlb + (size_t)cc * D + hl * 4);
            }
            #pragma unroll
            for (int u = 0; u < 8; ++u) {
                a0 = fmaf(nn[u], __uint_as_float(dv[u].x << 16),         a0);
                a1 = fmaf(nn[u], __uint_as_float(dv[u].x & 0xFFFF0000u), a1);
                a2 = fmaf(nn[u], __uint_as_float(dv[u].y << 16),         a2);
                a3 = fmaf(nn[u], __uint_as_float(dv[u].y & 0xFFFF0000u), a3);
            }
        }
    }
    // combine halves: half-1 partials live in lane hl+32
    float b0 = __shfl(a0, hl + 32);
    float b1 = __shfl(a1, hl + 32);
    float b2 = __shfl(a2, hl + 32);
    float b3 = __shfl(a3, hl + 32);
    if (half == 0) {
        float4 o = make_float4(a0 + b0, a1 + b1, a2 + b2, a3 + b3);
        *(float4*)(out + (size_t)i * D + hl * 4) = o;
    }
}

// ======================= fallback (R1 atomic path) =======================
__global__ __launch_bounds__(256) void k_zero(int* __restrict__ p, int n) {
    int i = blockIdx.x * 256 + threadIdx.x;
    if (i < n) p[i] = 0;
}
__global__ __launch_bounds__(256) void k_deg(const int* __restrict__ cols,
                                             int* __restrict__ cntc, int E) {
    int e = blockIdx.x * 256 + threadIdx.x;
    if (e < E) atomicAdd(&cntc[cols[e]], 1);
}
#define GEMM_R 8
__global__ __launch_bounds__(128) void k_gemmf(const float* __restrict__ x,
                                               const float* __restrict__ W,
                                               const float* __restrict__ b,
                                               float* __restrict__ xl, int N) {
    __shared__ float xs[GEMM_R][D];
    const int c  = threadIdx.x;
    const int r0 = blockIdx.x * GEMM_R;
    #pragma unroll
    for (int r = 0; r < GEMM_R; ++r) {
        int row = r0 + r;
        xs[r][c] = (row < N) ? x[row * D + c] : 0.0f;
    }
    __syncthreads();
    float acc[GEMM_R];
    const float bc = b[c];
    #pragma unroll
    for (int r = 0; r < GEMM_R; ++r) acc[r] = bc;
    for (int k = 0; k < D; k += 4) {
        const float w0 = W[(k + 0) * D + c];
        const float w1 = W[(k + 1) * D + c];
        const float w2 = W[(k + 2) * D + c];
        const float w3 = W[(k + 3) * D + c];
        #pragma unroll
        for (int r = 0; r < GEMM_R; ++r) {
            const float4 xv = *reinterpret_cast<const float4*>(&xs[r][k]);
            acc[r] = fmaf(xv.x, w0, acc[r]);
            acc[r] = fmaf(xv.y, w1, acc[r]);
            acc[r] = fmaf(xv.z, w2, acc[r]);
            acc[r] = fmaf(xv.w, w3, acc[r]);
        }
    }
    #pragma unroll
    for (int r = 0; r < GEMM_R; ++r) {
        int row = r0 + r;
        if (row < N) xl[row * D + c] = acc[r];
    }
}
__global__ __launch_bounds__(256) void k_self(const float* __restrict__ xl,
                                              const float* __restrict__ dis,
                                              float* __restrict__ out, int N) {
    int gid = blockIdx.x * 256 + threadIdx.x;
    int i = gid >> 7;
    if (i < N) {
        float d = dis[i];
        out[gid] = d * d * xl[gid];
    }
}
__global__ __launch_bounds__(256) void k_scatter(const int* __restrict__ rows,
                                                 const int* __restrict__ cols,
                                                 const float* __restrict__ dis,
                                                 const float* __restrict__ xl,
                                                 float* __restrict__ out, int E) {
    long long gid = (long long)blockIdx.x * 256 + threadIdx.x;
    int e    = (int)(gid >> 6);
    int lane = (int)(gid & 63);
    if (e >= E) return;
    const int row = rows[e];
    const int col = cols[e];
    const float nrm = dis[row] * dis[col];
    atomicAdd(&out[row * D + lane],      nrm * xl[col * D + lane]);
    atomicAdd(&out[row * D + 64 + lane], nrm * xl[col * D + 64 + lane]);
}

// ======================= launch ==========================================
extern "C" void kernel_launch(void* const* d_in, const int* in_sizes, int n_in,
                              void* d_out, int out_size, void* d_ws, size_t ws_size,
                              hipStream_t stream) {
    const float* x   = (const float*)d_in[0];
    const int*   ei  = (const int*)d_in[1];
    const float* W   = (const float*)d_in[2];
    const float* b   = (const float*)d_in[3];
    float*       out = (float*)d_out;

    const int N = in_sizes[0] / D;   // 50000
    const int E = in_sizes[1] / 2;   // 1.6M
    const int* rows = ei;
    const int* cols = ei + E;
    const int NB = (N + RPB - 1) / RPB;        // 196
    const int NT = (E + TILE - 1) / TILE;      // 196
    const int CAP = (((2 * E) / NB) + 63) / 64 * 64;   // 2x mean bucket -> 16384

    int colshift = 0;
    while (((N - 1) >> colshift) >= CSEG) ++colshift;  // N=50000 -> 12

    // ws layout
    char* p = (char*)d_ws;
    size_t off = 0;
    unsigned short* xlb  = (unsigned short*)(p + off); off += (size_t)N * D * 2;
    unsigned short* wtb  = (unsigned short*)(p + off); off += (size_t)D * D * 2;
    float*          dis  = (float*)(p + off);          off += (size_t)N * 4;
    int*            cntc = (int*)(p + off);            off += (size_t)N * 4;
    int*            bcur = (int*)(p + off);            off += (size_t)MAXB * 4;
    int*            begN = (int*)(p + off);            off += (size_t)N * 4;
    int*            endN = (int*)(p + off);            off += (size_t)N * 4;
    unsigned*       ebuf = (unsigned*)(p + off);       off += (size_t)NB * CAP * 4;
    unsigned short* ecol = (unsigned short*)(p + off); off += (size_t)NB * CAP * 2;

    const int gN = (N + 255) / 256;
    const int gE = (E + 255) / 256;

    if (N <= 65536 && NB <= MAXB && CAP <= SPLIT_CAP && ws_size >= off) {
        k_prep  <<<gN, 256, 0, stream>>>(W, wtb, cntc, bcur, N, NB, CAP);
        k_bin   <<<NT, BINB, 0, stream>>>(rows, cols, bcur, ebuf, E, NB, CAP);
        k_deg2  <<<DTIL * DSEG, 1024, 0, stream>>>(cols, cntc, E, N);
        k_dis   <<<gN, 256, 0, stream>>>(cntc, dis, N);
        k_split <<<NB, 1024, 0, stream>>>(bcur, ebuf, ecol, begN, endN, N, CAP, colshift);
        k_gemm  <<<(N + 63) / 64, 256, 0, stream>>>(x, wtb, b, xlb, N);
        k_reduce<<<(N + 3) / 4, 256, 0, stream>>>(begN, endN, ecol, dis, xlb, out, N);
    } else {
        // fallback: R1 atomic scatter path (fp32 xl)
        char* q = (char*)d_ws;
        float* xl   = (float*)q;
        float* disF = (float*)(q + (size_t)N * D * 4);
        int*   cc   = (int*)(q + (size_t)N * D * 4 + (size_t)N * 4);
        k_zero <<<gN, 256, 0, stream>>>(cc, N);
        k_deg  <<<gE, 256, 0, stream>>>(cols, cc, E);
        k_dis  <<<gN, 256, 0, stream>>>(cc, disF, N);
        k_gemmf<<<(N + GEMM_R - 1) / GEMM_R, 128, 0, stream>>>(x, W, b, xl, N);
        k_self <<<((N * D) + 255) / 256, 256, 0, stream>>>(xl, disF, out, N);
        long long st = (long long)E * 64;
        k_scatter<<<(int)((st + 255) / 256), 256, 0, stream>>>(rows, cols, disF, xl, out, E);
    }
}

// Round 12
// 198.992 us; speedup vs baseline: 1.0058x; 1.0058x over previous
//
#include <hip/hip_runtime.h>
#include <hip/hip_bf16.h>

// GCNConv: out[i] = sum_{e: row[e]=i} dis[row]*dis[col]*xl[col] + dis[i]^2*xl[i]
// N=50000, E=1.6M, D=128, fp32 in/out.
//
// R11 -> R12 (cleanup; R11's two levers both failed informatively):
//  - k_reduce: revert to R10 full-wave ushort2 form (53.4 -> 51us; half-wave
//    proved the kernel is at the random-256B HBM ceiling ~3.5 TB/s, not
//    VALU/MLP bound).
//  - k_split: revert to 256-key counting sort (CSEG bought nothing).
//  - k_deg2: DSEG 4->2 via 100KB LDS int hist; cols swept 2x not 4x.

#define D     128
#define TILE  8192
#define BINB  1024      // k_bin block size
#define RPB   256       // rows per bucket
#define MAXB  256       // bucket id must fit 8 bits
#define SPLIT_CAP 16384 // LDS sort capacity (= CAP for N=50000/E=1.6M)
#define DSEG  2         // degree histogram segments (100KB LDS each)
#define DTIL  32        // degree histogram tiles over E

typedef short  bf16x8 __attribute__((ext_vector_type(8)));
typedef float  f32x4  __attribute__((ext_vector_type(4)));
typedef unsigned short us4 __attribute__((ext_vector_type(4)));
typedef unsigned short us8 __attribute__((ext_vector_type(8)));

static __device__ __forceinline__ unsigned short f2bf(float f) {
    unsigned u = __float_as_uint(f);
    u = (u + 0x7FFFu + ((u >> 16) & 1u)) >> 16;   // RNE
    return (unsigned short)u;
}
static __device__ __forceinline__ float bf2f(unsigned short s) {
    return __uint_as_float(((unsigned)s) << 16);
}

// --- init: cntc=0, bcur[b]=b*CAP, wtb = bf16(W^T) ------------------------
__global__ __launch_bounds__(256) void k_prep(const float* __restrict__ W,
                                              unsigned short* __restrict__ wtb,
                                              int* __restrict__ cntc,
                                              int* __restrict__ bcur,
                                              int N, int NB, int CAP) {
    int i = blockIdx.x * 256 + threadIdx.x;
    if (i < N) cntc[i] = 0;
    if (i < NB) bcur[i] = i * CAP;
    if (i < D * D) {
        int n = i >> 7, k = i & 127;
        wtb[n * 128 + k] = f2bf(W[k * 128 + n]);
    }
}

// --- single-pass bin into fixed-stride bucket regions --------------------
__global__ __launch_bounds__(BINB) void k_bin(const int* __restrict__ rows,
                                              const int* __restrict__ cols,
                                              int* __restrict__ bcur,
                                              unsigned* __restrict__ ebuf,
                                              int E, int NB, int CAP) {
    __shared__ int lcnt[MAXB];
    __shared__ int lbase[MAXB];
    const int t = threadIdx.x;
    const int base = blockIdx.x * TILE;
    int m = E - base; if (m > TILE) m = TILE;

    unsigned p[TILE / BINB];
    #pragma unroll
    for (int it = 0; it < TILE / BINB; ++it) {
        int i = it * BINB + t;
        if (i < m) {
            unsigned r = (unsigned)rows[base + i];
            unsigned c = (unsigned)cols[base + i];
            p[it] = c | ((r & 255u) << 16) | ((r >> 8) << 24);
        }
    }
    for (int b = t; b < NB; b += BINB) lcnt[b] = 0;
    __syncthreads();
    #pragma unroll
    for (int it = 0; it < TILE / BINB; ++it) {
        int i = it * BINB + t;
        if (i < m) atomicAdd(&lcnt[p[it] >> 24], 1);
    }
    __syncthreads();
    for (int b = t; b < NB; b += BINB) {
        int c = lcnt[b];
        lbase[b] = c ? atomicAdd(&bcur[b], c) : 0;
        lcnt[b] = 0;
    }
    __syncthreads();
    #pragma unroll
    for (int it = 0; it < TILE / BINB; ++it) {
        int i = it * BINB + t;
        if (i < m) {
            int bk = p[it] >> 24;
            int r  = atomicAdd(&lcnt[bk], 1);
            int pos = lbase[bk] + r;
            if (pos < (bk + 1) * CAP)               // overflow guard (never fires)
                ebuf[pos] = p[it] & 0xFFFFFFu;      // col | rowlocal<<16
        }
    }
}

// --- degree: 2-segment LDS histogram, 100KB per block --------------------
__global__ __launch_bounds__(1024) void k_deg2(const int* __restrict__ cols,
                                               int* __restrict__ cntc,
                                               int E, int N) {
    const int segw = (N + DSEG - 1) / DSEG;         // 25000
    __shared__ int h[25088];                        // >= segw, 100KB
    const int seg  = blockIdx.x & (DSEG - 1);
    const int tile = blockIdx.x >> 1;               // DSEG==2
    const int lo = seg * segw;
    const int hi = min(lo + segw, N);
    const int w  = hi - lo;
    for (int i = threadIdx.x; i < w; i += 1024) h[i] = 0;
    __syncthreads();
    const int per = (E + DTIL - 1) / DTIL;
    const int beg = tile * per;
    const int end = min(beg + per, E);
    for (int i = beg + threadIdx.x; i < end; i += 1024) {
        int c = cols[i];
        if (c >= lo && c < hi) atomicAdd(&h[c - lo], 1);
    }
    __syncthreads();
    for (int i = threadIdx.x; i < w; i += 1024) {
        int v = h[i];
        if (v) atomicAdd(&cntc[lo + i], v);         // coalesced merge
    }
}

// --- dis = rsqrt(deg_col + 1) --------------------------------------------
__global__ __launch_bounds__(256) void k_dis(const int* __restrict__ cntc,
                                             float* __restrict__ dis, int N) {
    int i = blockIdx.x * 256 + threadIdx.x;
    if (i < N) dis[i] = rsqrtf((float)(cntc[i] + 1));
}

// --- per-bucket counting sort staged in LDS, linear global writes --------
__global__ __launch_bounds__(1024) void k_split(const int* __restrict__ bcur,
                                                const unsigned* __restrict__ ebuf,
                                                unsigned short* __restrict__ ecol,
                                                int* __restrict__ begN,
                                                int* __restrict__ endN,
                                                int N, int CAP) {
    __shared__ unsigned short sorted[SPLIT_CAP];    // 32 KB
    __shared__ int cnt[RPB];
    __shared__ int excl[RPB];
    __shared__ int cur[RPB];
    const int b = blockIdx.x, t = threadIdx.x;
    const int base = b * CAP;
    int m = bcur[b] - base; if (m > CAP) m = CAP;
    if (t < RPB) cnt[t] = 0;
    __syncthreads();
    for (int i = t; i < m; i += 1024)
        atomicAdd(&cnt[(ebuf[base + i] >> 16) & 255], 1);
    __syncthreads();
    if (t == 0) {
        int s = 0;
        #pragma unroll
        for (int r = 0; r < RPB; ++r) { excl[r] = s; s += cnt[r]; }
    }
    __syncthreads();
    const int row0 = b * RPB;
    if (t < RPB) {
        cur[t] = excl[t];
        if (row0 + t < N) {
            begN[row0 + t] = base + excl[t];
            endN[row0 + t] = base + excl[t] + cnt[t];
        }
    }
    __syncthreads();
    for (int i = t; i < m; i += 1024) {
        unsigned p = ebuf[base + i];
        int pos = atomicAdd(&cur[(p >> 16) & 255], 1);
        sorted[pos] = (unsigned short)(p & 0xFFFFu);   // random scatter in LDS
    }
    __syncthreads();
    for (int i = t; i < m; i += 1024)
        ecol[base + i] = sorted[i];                     // linear coalesced write
}

// --- MFMA bf16 GEMM: xlb = bf16(x @ W + b), 64x128 tile per block --------
__global__ __launch_bounds__(256) void k_gemm(const float* __restrict__ x,
                                              const unsigned short* __restrict__ wtb,
                                              const float* __restrict__ bia,
                                              unsigned short* __restrict__ xlb,
                                              int N) {
    __shared__ unsigned short wt[128][136];   // W^T bf16, pad 8 -> 16B-aligned rows
    __shared__ unsigned short xs[64][136];    // x tile bf16
    const int t = threadIdx.x;
    const int row0 = blockIdx.x * 64;

    #pragma unroll
    for (int i = 0; i < 8; ++i) {             // W^T: 2048 ushort8, ds_write_b128
        int j = i * 256 + t;
        int n = j >> 4, k8 = j & 15;
        us8 v = *(const us8*)&wtb[j * 8];
        *(us8*)&wt[n][k8 * 8] = v;
    }
    #pragma unroll
    for (int i = 0; i < 8; ++i) {             // x: 2048 float4 -> ushort4
        int j = i * 256 + t;
        int r = j >> 5, c4 = j & 31;
        int gr = row0 + r;
        us4 o = (us4){0, 0, 0, 0};
        if (gr < N) {
            float4 v = *(const float4*)&x[(size_t)gr * D + c4 * 4];
            o = (us4){f2bf(v.x), f2bf(v.y), f2bf(v.z), f2bf(v.w)};
        }
        *(us4*)&xs[r][c4 * 4] = o;
    }
    __syncthreads();

    const int w  = t >> 6, l = t & 63;
    const int m0 = w * 16;
    const int lm = l & 15, lq = l >> 4;

    f32x4 acc[8];
    #pragma unroll
    for (int nt = 0; nt < 8; ++nt) acc[nt] = (f32x4){0.f, 0.f, 0.f, 0.f};

    #pragma unroll
    for (int kk = 0; kk < 4; ++kk) {
        const int kof = kk * 32 + lq * 8;
        bf16x8 a = *(const bf16x8*)&xs[m0 + lm][kof];
        #pragma unroll
        for (int nt = 0; nt < 8; ++nt) {
            bf16x8 bb = *(const bf16x8*)&wt[nt * 16 + lm][kof];
            acc[nt] = __builtin_amdgcn_mfma_f32_16x16x32_bf16(a, bb, acc[nt], 0, 0, 0);
        }
    }

    #pragma unroll
    for (int nt = 0; nt < 8; ++nt) {
        const int col = nt * 16 + lm;
        const float bc = bia[col];
        #pragma unroll
        for (int r = 0; r < 4; ++r) {
            int grow = row0 + m0 + lq * 4 + r;
            if (grow < N) xlb[(size_t)grow * D + col] = f2bf(acc[nt][r] + bc);
        }
    }
}

// --- wave-per-node gather-reduce (no LDS, no barriers) -------------------
__global__ __launch_bounds__(256) void k_reduce(const int* __restrict__ begN,
                                                const int* __restrict__ endN,
                                                const unsigned short* __restrict__ ecol,
                                                const float* __restrict__ dis,
                                                const unsigned short* __restrict__ xlb,
                                                float* __restrict__ out, int N) {
    const int wave = threadIdx.x >> 6;
    const int lane = threadIdx.x & 63;
    const int i = blockIdx.x * 4 + wave;
    if (i >= N) return;
    const float di = dis[i];

    // self loop
    const ushort2 sv = *reinterpret_cast<const ushort2*>(xlb + (size_t)i * D + lane * 2);
    float ax = di * di * bf2f(sv.x);
    float ay = di * di * bf2f(sv.y);

    const int beg = begN[i], end = endN[i];
    for (int base = beg; base < end; base += 64) {
        int m = end - base; if (m > 64) m = 64;
        int   c = 0;
        float n = 0.0f;
        if (lane < m) {
            c = ecol[base + lane];
            n = di * dis[c];
        }
        for (int j = 0; j < m; j += 8) {
            float vx[8], vy[8], nn[8];
            #pragma unroll
            for (int u = 0; u < 8; ++u) {          // 8 independent 256B gathers
                int cc = __shfl(c, j + u);         // lanes >= m carry c=0,n=0
                ushort2 s = *reinterpret_cast<const ushort2*>(xlb + (size_t)cc * D + lane * 2);
                vx[u] = bf2f(s.x);
                vy[u] = bf2f(s.y);
                nn[u] = __shfl(n, j + u);
            }
            #pragma unroll
            for (int u = 0; u < 8; ++u) {
                ax = fmaf(nn[u], vx[u], ax);
                ay = fmaf(nn[u], vy[u], ay);
            }
        }
    }
    *reinterpret_cast<float2*>(out + (size_t)i * D + lane * 2) = make_float2(ax, ay);
}

// ======================= fallback (R1 atomic path) =======================
__global__ __launch_bounds__(256) void k_zero(int* __restrict__ p, int n) {
    int i = blockIdx.x * 256 + threadIdx.x;
    if (i < n) p[i] = 0;
}
__global__ __launch_bounds__(256) void k_deg(const int* __restrict__ cols,
                                             int* __restrict__ cntc, int E) {
    int e = blockIdx.x * 256 + threadIdx.x;
    if (e < E) atomicAdd(&cntc[cols[e]], 1);
}
#define GEMM_R 8
__global__ __launch_bounds__(128) void k_gemmf(const float* __restrict__ x,
                                               const float* __restrict__ W,
                                               const float* __restrict__ b,
                                               float* __restrict__ xl, int N) {
    __shared__ float xs[GEMM_R][D];
    const int c  = threadIdx.x;
    const int r0 = blockIdx.x * GEMM_R;
    #pragma unroll
    for (int r = 0; r < GEMM_R; ++r) {
        int row = r0 + r;
        xs[r][c] = (row < N) ? x[row * D + c] : 0.0f;
    }
    __syncthreads();
    float acc[GEMM_R];
    const float bc = b[c];
    #pragma unroll
    for (int r = 0; r < GEMM_R; ++r) acc[r] = bc;
    for (int k = 0; k < D; k += 4) {
        const float w0 = W[(k + 0) * D + c];
        const float w1 = W[(k + 1) * D + c];
        const float w2 = W[(k + 2) * D + c];
        const float w3 = W[(k + 3) * D + c];
        #pragma unroll
        for (int r = 0; r < GEMM_R; ++r) {
            const float4 xv = *reinterpret_cast<const float4*>(&xs[r][k]);
            acc[r] = fmaf(xv.x, w0, acc[r]);
            acc[r] = fmaf(xv.y, w1, acc[r]);
            acc[r] = fmaf(xv.z, w2, acc[r]);
            acc[r] = fmaf(xv.w, w3, acc[r]);
        }
    }
    #pragma unroll
    for (int r = 0; r < GEMM_R; ++r) {
        int row = r0 + r;
        if (row < N) xl[row * D + c] = acc[r];
    }
}
__global__ __launch_bounds__(256) void k_self(const float* __restrict__ xl,
                                              const float* __restrict__ dis,
                                              float* __restrict__ out, int N) {
    int gid = blockIdx.x * 256 + threadIdx.x;
    int i = gid >> 7;
    if (i < N) {
        float d = dis[i];
        out[gid] = d * d * xl[gid];
    }
}
__global__ __launch_bounds__(256) void k_scatter(const int* __restrict__ rows,
                                                 const int* __restrict__ cols,
                                                 const float* __restrict__ dis,
                                                 const float* __restrict__ xl,
                                                 float* __restrict__ out, int E) {
    long long gid = (long long)blockIdx.x * 256 + threadIdx.x;
    int e    = (int)(gid >> 6);
    int lane = (int)(gid & 63);
    if (e >= E) return;
    const int row = rows[e];
    const int col = cols[e];
    const float nrm = dis[row] * dis[col];
    atomicAdd(&out[row * D + lane],      nrm * xl[col * D + lane]);
    atomicAdd(&out[row * D + 64 + lane], nrm * xl[col * D + 64 + lane]);
}

// ======================= launch ==========================================
extern "C" void kernel_launch(void* const* d_in, const int* in_sizes, int n_in,
                              void* d_out, int out_size, void* d_ws, size_t ws_size,
                              hipStream_t stream) {
    const float* x   = (const float*)d_in[0];
    const int*   ei  = (const int*)d_in[1];
    const float* W   = (const float*)d_in[2];
    const float* b   = (const float*)d_in[3];
    float*       out = (float*)d_out;

    const int N = in_sizes[0] / D;   // 50000
    const int E = in_sizes[1] / 2;   // 1.6M
    const int* rows = ei;
    const int* cols = ei + E;
    const int NB = (N + RPB - 1) / RPB;        // 196
    const int NT = (E + TILE - 1) / TILE;      // 196
    const int CAP = (((2 * E) / NB) + 63) / 64 * 64;   // 2x mean bucket -> 16384

    // ws layout
    char* p = (char*)d_ws;
    size_t off = 0;
    unsigned short* xlb  = (unsigned short*)(p + off); off += (size_t)N * D * 2;
    unsigned short* wtb  = (unsigned short*)(p + off); off += (size_t)D * D * 2;
    float*          dis  = (float*)(p + off);          off += (size_t)N * 4;
    int*            cntc = (int*)(p + off);            off += (size_t)N * 4;
    int*            bcur = (int*)(p + off);            off += (size_t)MAXB * 4;
    int*            begN = (int*)(p + off);            off += (size_t)N * 4;
    int*            endN = (int*)(p + off);            off += (size_t)N * 4;
    unsigned*       ebuf = (unsigned*)(p + off);       off += (size_t)NB * CAP * 4;
    unsigned short* ecol = (unsigned short*)(p + off); off += (size_t)NB * CAP * 2;

    const int gN = (N + 255) / 256;
    const int gE = (E + 255) / 256;

    if (N <= 65536 && NB <= MAXB && CAP <= SPLIT_CAP && ws_size >= off) {
        k_prep  <<<gN, 256, 0, stream>>>(W, wtb, cntc, bcur, N, NB, CAP);
        k_bin   <<<NT, BINB, 0, stream>>>(rows, cols, bcur, ebuf, E, NB, CAP);
        k_deg2  <<<DTIL * DSEG, 1024, 0, stream>>>(cols, cntc, E, N);
        k_dis   <<<gN, 256, 0, stream>>>(cntc, dis, N);
        k_split <<<NB, 1024, 0, stream>>>(bcur, ebuf, ecol, begN, endN, N, CAP);
        k_gemm  <<<(N + 63) / 64, 256, 0, stream>>>(x, wtb, b, xlb, N);
        k_reduce<<<(N + 3) / 4, 256, 0, stream>>>(begN, endN, ecol, dis, xlb, out, N);
    } else {
        // fallback: R1 atomic scatter path (fp32 xl)
        char* q = (char*)d_ws;
        float* xl   = (float*)q;
        float* disF = (float*)(q + (size_t)N * D * 4);
        int*   cc   = (int*)(q + (size_t)N * D * 4 + (size_t)N * 4);
        k_zero <<<gN, 256, 0, stream>>>(cc, N);
        k_deg  <<<gE, 256, 0, stream>>>(cols, cc, E);
        k_dis  <<<gN, 256, 0, stream>>>(cc, disF, N);
        k_gemmf<<<(N + GEMM_R - 1) / GEMM_R, 128, 0, stream>>>(x, W, b, xl, N);
        k_self <<<((N * D) + 255) / 256, 256, 0, stream>>>(xl, disF, out, N);
        long long st = (long long)E * 64;
        k_scatter<<<(int)((st + 255) / 256), 256, 0, stream>>>(rows, cols, disF, xl, out, E);
    }
}

// Round 13
// 177.549 us; speedup vs baseline: 1.1273x; 1.1208x over previous
//
#include <hip/hip_runtime.h>
#include <hip/hip_bf16.h>

// GCNConv: out[i] = sum_{e: row[e]=i} dis[row]*dis[col]*xl[col] + dis[i]^2*xl[i]
// N=50000, E=1.6M, D=128, fp32 in/out.
//
// R12 -> R13: build kernels sum to ~138us; model: bound by L2 TRANSACTION
// count (~40G/s), not bytes.
//  - k_bin: in-LDS tile sort, positional coalesced writes (runs ~21) ->
//    ~3 transactions/wave instead of 64. TILE 4096 (391 blocks, full CU cover).
//  - degree: col-keyed 1-byte binning in k_bin + k_degdis LDS hist ->
//    replaces k_deg2 (12.8MB sweeps + 1.6M global atomics) + k_dis.
//  - wave shfl scans replace serial t0 scans (k_bin, k_split).

#define D     128
#define TILE  4096
#define BINB  1024      // k_bin block size
#define RPB   256       // rows per bucket
#define MAXB  256       // bucket id must fit 8 bits
#define SPLIT_CAP 16384 // LDS sort capacity (= CAP for N=50000/E=1.6M)

typedef short  bf16x8 __attribute__((ext_vector_type(8)));
typedef float  f32x4  __attribute__((ext_vector_type(4)));
typedef unsigned short us4 __attribute__((ext_vector_type(4)));
typedef unsigned short us8 __attribute__((ext_vector_type(8)));

static __device__ __forceinline__ unsigned short f2bf(float f) {
    unsigned u = __float_as_uint(f);
    u = (u + 0x7FFFu + ((u >> 16) & 1u)) >> 16;   // RNE
    return (unsigned short)u;
}
static __device__ __forceinline__ float bf2f(unsigned short s) {
    return __uint_as_float(((unsigned)s) << 16);
}

// --- init: bcur[b]=b*CAP, bcurC[b]=b*CAPC, wtb = bf16(W^T) ---------------
__global__ __launch_bounds__(256) void k_prep(const float* __restrict__ W,
                                              unsigned short* __restrict__ wtb,
                                              int* __restrict__ bcur,
                                              int* __restrict__ bcurC,
                                              int NB, int CAP, int CAPC) {
    int i = blockIdx.x * 256 + threadIdx.x;
    if (i < NB) { bcur[i] = i * CAP; bcurC[i] = i * CAPC; }
    if (i < D * D) {
        int n = i >> 7, k = i & 127;
        wtb[n * 128 + k] = f2bf(W[k * 128 + n]);
    }
}

// --- bin: in-LDS dual sort (row-key + col-key), coalesced region writes --
__global__ __launch_bounds__(BINB) void k_bin(const int* __restrict__ rows,
                                              const int* __restrict__ cols,
                                              int* __restrict__ bcur,
                                              int* __restrict__ bcurC,
                                              unsigned* __restrict__ ebuf,
                                              unsigned char* __restrict__ cebuf,
                                              int E, int NB, int CAP, int CAPC) {
    __shared__ unsigned sorted[TILE];          // 16 KB
    __shared__ unsigned short sortedC[TILE];   // 8 KB
    __shared__ int lcnt[MAXB], lbase[MAXB], excl[MAXB], cur[MAXB];
    __shared__ int lcntC[MAXB], lbaseC[MAXB], exclC[MAXB], curC[MAXB];
    const int t = threadIdx.x;
    const int base = blockIdx.x * TILE;
    int m = E - base; if (m > TILE) m = TILE;

    unsigned p[TILE / BINB];
    unsigned short q[TILE / BINB];
    #pragma unroll
    for (int it = 0; it < TILE / BINB; ++it) {
        int i = it * BINB + t;
        if (i < m) {
            unsigned r = (unsigned)rows[base + i];
            unsigned c = (unsigned)cols[base + i];
            p[it] = c | ((r & 255u) << 16) | ((r >> 8) << 24);
            q[it] = (unsigned short)c;           // bucket = c>>8, local = c&255
        }
    }
    for (int b = t; b < MAXB; b += BINB) { lcnt[b] = 0; lcntC[b] = 0; }
    __syncthreads();
    #pragma unroll
    for (int it = 0; it < TILE / BINB; ++it) {
        int i = it * BINB + t;
        if (i < m) {
            atomicAdd(&lcnt[p[it] >> 24], 1);
            atomicAdd(&lcntC[q[it] >> 8], 1);
        }
    }
    __syncthreads();
    // wave 0: row scan; wave 1: col scan (shfl ladders, register-only)
    if (t < 64) {
        int b4 = t * 4;
        int v0 = lcnt[b4], v1 = lcnt[b4+1], v2 = lcnt[b4+2], v3 = lcnt[b4+3];
        int s = v0+v1+v2+v3, inc = s;
        #pragma unroll
        for (int off = 1; off < 64; off <<= 1) { int o = __shfl_up(inc, off); if (t >= off) inc += o; }
        int ex = inc - s;
        excl[b4] = ex; excl[b4+1] = ex+v0; excl[b4+2] = ex+v0+v1; excl[b4+3] = ex+v0+v1+v2;
    } else if (t < 128) {
        int l = t - 64, b4 = l * 4;
        int v0 = lcntC[b4], v1 = lcntC[b4+1], v2 = lcntC[b4+2], v3 = lcntC[b4+3];
        int s = v0+v1+v2+v3, inc = s;
        #pragma unroll
        for (int off = 1; off < 64; off <<= 1) { int o = __shfl_up(inc, off); if (l >= off) inc += o; }
        int ex = inc - s;
        exclC[b4] = ex; exclC[b4+1] = ex+v0; exclC[b4+2] = ex+v0+v1; exclC[b4+3] = ex+v0+v1+v2;
    }
    for (int b = t; b < NB; b += BINB) {     // reserve global regions
        int c = lcnt[b];
        lbase[b] = c ? atomicAdd(&bcur[b], c) : 0;
        int cc = lcntC[b];
        lbaseC[b] = cc ? atomicAdd(&bcurC[b], cc) : 0;
    }
    __syncthreads();
    for (int b = t; b < NB; b += BINB) { cur[b] = excl[b]; curC[b] = exclC[b]; }
    __syncthreads();
    #pragma unroll
    for (int it = 0; it < TILE / BINB; ++it) {  // scatter into LDS (random: free)
        int i = it * BINB + t;
        if (i < m) {
            int pos  = atomicAdd(&cur[p[it] >> 24], 1);
            sorted[pos] = p[it];
            int posC = atomicAdd(&curC[q[it] >> 8], 1);
            sortedC[posC] = q[it];
        }
    }
    __syncthreads();
    #pragma unroll
    for (int it = 0; it < TILE / BINB; ++it) {  // positional coalesced writes
        int i = it * BINB + t;
        if (i < m) {
            unsigned pp = sorted[i];
            int bk = pp >> 24;
            int g  = lbase[bk] + i - excl[bk];
            if (g < (bk + 1) * CAP) ebuf[g] = pp & 0xFFFFFFu;
            unsigned short qq = sortedC[i];
            int bc = qq >> 8;
            int gc = lbaseC[bc] + i - exclC[bc];
            if (gc < (bc + 1) * CAPC) cebuf[gc] = (unsigned char)(qq & 255u);
        }
    }
}

// --- degree + dis from col-bucket regions (1 block = 256 nodes) ----------
__global__ __launch_bounds__(256) void k_degdis(const int* __restrict__ bcurC,
                                                const unsigned char* __restrict__ cebuf,
                                                float* __restrict__ dis,
                                                int N, int CAPC) {
    __shared__ int cnt[RPB];
    const int b = blockIdx.x, t = threadIdx.x;
    const int base = b * CAPC;
    int m = bcurC[b] - base; if (m > CAPC) m = CAPC;
    cnt[t] = 0;
    __syncthreads();
    const unsigned* cw = (const unsigned*)(cebuf + base);   // base 4-aligned
    int nw = m >> 2;
    for (int i = t; i < nw; i += 256) {
        unsigned u = cw[i];
        atomicAdd(&cnt[u & 255u], 1);
        atomicAdd(&cnt[(u >> 8) & 255u], 1);
        atomicAdd(&cnt[(u >> 16) & 255u], 1);
        atomicAdd(&cnt[u >> 24], 1);
    }
    if (t < (m & 3)) atomicAdd(&cnt[cebuf[base + nw * 4 + t]], 1);
    __syncthreads();
    int node = b * RPB + t;
    if (node < N) dis[node] = rsqrtf((float)(cnt[t] + 1));
}

// --- per-bucket counting sort staged in LDS, linear global writes --------
__global__ __launch_bounds__(1024) void k_split(const int* __restrict__ bcur,
                                                const unsigned* __restrict__ ebuf,
                                                unsigned short* __restrict__ ecol,
                                                int* __restrict__ begN,
                                                int* __restrict__ endN,
                                                int N, int CAP) {
    __shared__ unsigned short sorted[SPLIT_CAP];    // 32 KB
    __shared__ int cnt[RPB];
    __shared__ int excl[RPB];
    __shared__ int cur[RPB];
    const int b = blockIdx.x, t = threadIdx.x;
    const int base = b * CAP;
    int m = bcur[b] - base; if (m > CAP) m = CAP;
    if (t < RPB) cnt[t] = 0;
    __syncthreads();
    for (int i = t; i < m; i += 1024)
        atomicAdd(&cnt[(ebuf[base + i] >> 16) & 255], 1);
    __syncthreads();
    if (t < 64) {                                   // wave scan of 256 keys
        int b4 = t * 4;
        int v0 = cnt[b4], v1 = cnt[b4+1], v2 = cnt[b4+2], v3 = cnt[b4+3];
        int s = v0+v1+v2+v3, inc = s;
        #pragma unroll
        for (int off = 1; off < 64; off <<= 1) { int o = __shfl_up(inc, off); if (t >= off) inc += o; }
        int ex = inc - s;
        excl[b4] = ex; excl[b4+1] = ex+v0; excl[b4+2] = ex+v0+v1; excl[b4+3] = ex+v0+v1+v2;
    }
    __syncthreads();
    const int row0 = b * RPB;
    if (t < RPB) {
        cur[t] = excl[t];
        if (row0 + t < N) {
            begN[row0 + t] = base + excl[t];
            endN[row0 + t] = base + excl[t] + cnt[t];
        }
    }
    __syncthreads();
    for (int i = t; i < m; i += 1024) {
        unsigned p = ebuf[base + i];
        int pos = atomicAdd(&cur[(p >> 16) & 255], 1);
        sorted[pos] = (unsigned short)(p & 0xFFFFu);   // random scatter in LDS
    }
    __syncthreads();
    for (int i = t; i < m; i += 1024)
        ecol[base + i] = sorted[i];                     // linear coalesced write
}

// --- MFMA bf16 GEMM: xlb = bf16(x @ W + b), 64x128 tile per block --------
__global__ __launch_bounds__(256) void k_gemm(const float* __restrict__ x,
                                              const unsigned short* __restrict__ wtb,
                                              const float* __restrict__ bia,
                                              unsigned short* __restrict__ xlb,
                                              int N) {
    __shared__ unsigned short wt[128][136];   // W^T bf16, pad 8 -> 16B-aligned rows
    __shared__ unsigned short xs[64][136];    // x tile bf16
    const int t = threadIdx.x;
    const int row0 = blockIdx.x * 64;

    #pragma unroll
    for (int i = 0; i < 8; ++i) {             // W^T: 2048 ushort8, ds_write_b128
        int j = i * 256 + t;
        int n = j >> 4, k8 = j & 15;
        us8 v = *(const us8*)&wtb[j * 8];
        *(us8*)&wt[n][k8 * 8] = v;
    }
    #pragma unroll
    for (int i = 0; i < 8; ++i) {             // x: 2048 float4 -> ushort4
        int j = i * 256 + t;
        int r = j >> 5, c4 = j & 31;
        int gr = row0 + r;
        us4 o = (us4){0, 0, 0, 0};
        if (gr < N) {
            float4 v = *(const float4*)&x[(size_t)gr * D + c4 * 4];
            o = (us4){f2bf(v.x), f2bf(v.y), f2bf(v.z), f2bf(v.w)};
        }
        *(us4*)&xs[r][c4 * 4] = o;
    }
    __syncthreads();

    const int w  = t >> 6, l = t & 63;
    const int m0 = w * 16;
    const int lm = l & 15, lq = l >> 4;

    f32x4 acc[8];
    #pragma unroll
    for (int nt = 0; nt < 8; ++nt) acc[nt] = (f32x4){0.f, 0.f, 0.f, 0.f};

    #pragma unroll
    for (int kk = 0; kk < 4; ++kk) {
        const int kof = kk * 32 + lq * 8;
        bf16x8 a = *(const bf16x8*)&xs[m0 + lm][kof];
        #pragma unroll
        for (int nt = 0; nt < 8; ++nt) {
            bf16x8 bb = *(const bf16x8*)&wt[nt * 16 + lm][kof];
            acc[nt] = __builtin_amdgcn_mfma_f32_16x16x32_bf16(a, bb, acc[nt], 0, 0, 0);
        }
    }

    #pragma unroll
    for (int nt = 0; nt < 8; ++nt) {
        const int col = nt * 16 + lm;
        const float bc = bia[col];
        #pragma unroll
        for (int r = 0; r < 4; ++r) {
            int grow = row0 + m0 + lq * 4 + r;
            if (grow < N) xlb[(size_t)grow * D + col] = f2bf(acc[nt][r] + bc);
        }
    }
}

// --- wave-per-node gather-reduce (no LDS, no barriers) -------------------
__global__ __launch_bounds__(256) void k_reduce(const int* __restrict__ begN,
                                                const int* __restrict__ endN,
                                                const unsigned short* __restrict__ ecol,
                                                const float* __restrict__ dis,
                                                const unsigned short* __restrict__ xlb,
                                                float* __restrict__ out, int N) {
    const int wave = threadIdx.x >> 6;
    const int lane = threadIdx.x & 63;
    const int i = blockIdx.x * 4 + wave;
    if (i >= N) return;
    const float di = dis[i];

    // self loop
    const ushort2 sv = *reinterpret_cast<const ushort2*>(xlb + (size_t)i * D + lane * 2);
    float ax = di * di * bf2f(sv.x);
    float ay = di * di * bf2f(sv.y);

    const int beg = begN[i], end = endN[i];
    for (int base = beg; base < end; base += 64) {
        int m = end - base; if (m > 64) m = 64;
        int   c = 0;
        float n = 0.0f;
        if (lane < m) {
            c = ecol[base + lane];
            n = di * dis[c];
        }
        for (int j = 0; j < m; j += 8) {
            float vx[8], vy[8], nn[8];
            #pragma unroll
            for (int u = 0; u < 8; ++u) {          // 8 independent 256B gathers
                int cc = __shfl(c, j + u);         // lanes >= m carry c=0,n=0
                ushort2 s = *reinterpret_cast<const ushort2*>(xlb + (size_t)cc * D + lane * 2);
                vx[u] = bf2f(s.x);
                vy[u] = bf2f(s.y);
                nn[u] = __shfl(n, j + u);
            }
            #pragma unroll
            for (int u = 0; u < 8; ++u) {
                ax = fmaf(nn[u], vx[u], ax);
                ay = fmaf(nn[u], vy[u], ay);
            }
        }
    }
    *reinterpret_cast<float2*>(out + (size_t)i * D + lane * 2) = make_float2(ax, ay);
}

// ======================= fallback (R1 atomic path) =======================
__global__ __launch_bounds__(256) void k_zero(int* __restrict__ p, int n) {
    int i = blockIdx.x * 256 + threadIdx.x;
    if (i < n) p[i] = 0;
}
__global__ __launch_bounds__(256) void k_deg(const int* __restrict__ cols,
                                             int* __restrict__ cntc, int E) {
    int e = blockIdx.x * 256 + threadIdx.x;
    if (e < E) atomicAdd(&cntc[cols[e]], 1);
}
__global__ __launch_bounds__(256) void k_dis(const int* __restrict__ cntc,
                                             float* __restrict__ dis, int N) {
    int i = blockIdx.x * 256 + threadIdx.x;
    if (i < N) dis[i] = rsqrtf((float)(cntc[i] + 1));
}
#define GEMM_R 8
__global__ __launch_bounds__(128) void k_gemmf(const float* __restrict__ x,
                                               const float* __restrict__ W,
                                               const float* __restrict__ b,
                                               float* __restrict__ xl, int N) {
    __shared__ float xs[GEMM_R][D];
    const int c  = threadIdx.x;
    const int r0 = blockIdx.x * GEMM_R;
    #pragma unroll
    for (int r = 0; r < GEMM_R; ++r) {
        int row = r0 + r;
        xs[r][c] = (row < N) ? x[row * D + c] : 0.0f;
    }
    __syncthreads();
    float acc[GEMM_R];
    const float bc = b[c];
    #pragma unroll
    for (int r = 0; r < GEMM_R; ++r) acc[r] = bc;
    for (int k = 0; k < D; k += 4) {
        const float w0 = W[(k + 0) * D + c];
        const float w1 = W[(k + 1) * D + c];
        const float w2 = W[(k + 2) * D + c];
        const float w3 = W[(k + 3) * D + c];
        #pragma unroll
        for (int r = 0; r < GEMM_R; ++r) {
            const float4 xv = *reinterpret_cast<const float4*>(&xs[r][k]);
            acc[r] = fmaf(xv.x, w0, acc[r]);
            acc[r] = fmaf(xv.y, w1, acc[r]);
            acc[r] = fmaf(xv.z, w2, acc[r]);
            acc[r] = fmaf(xv.w, w3, acc[r]);
        }
    }
    #pragma unroll
    for (int r = 0; r < GEMM_R; ++r) {
        int row = r0 + r;
        if (row < N) xl[row * D + c] = acc[r];
    }
}
__global__ __launch_bounds__(256) void k_self(const float* __restrict__ xl,
                                              const float* __restrict__ dis,
                                              float* __restrict__ out, int N) {
    int gid = blockIdx.x * 256 + threadIdx.x;
    int i = gid >> 7;
    if (i < N) {
        float d = dis[i];
        out[gid] = d * d * xl[gid];
    }
}
__global__ __launch_bounds__(256) void k_scatter(const int* __restrict__ rows,
                                                 const int* __restrict__ cols,
                                                 const float* __restrict__ dis,
                                                 const float* __restrict__ xl,
                                                 float* __restrict__ out, int E) {
    long long gid = (long long)blockIdx.x * 256 + threadIdx.x;
    int e    = (int)(gid >> 6);
    int lane = (int)(gid & 63);
    if (e >= E) return;
    const int row = rows[e];
    const int col = cols[e];
    const float nrm = dis[row] * dis[col];
    atomicAdd(&out[row * D + lane],      nrm * xl[col * D + lane]);
    atomicAdd(&out[row * D + 64 + lane], nrm * xl[col * D + 64 + lane]);
}

// ======================= launch ==========================================
extern "C" void kernel_launch(void* const* d_in, const int* in_sizes, int n_in,
                              void* d_out, int out_size, void* d_ws, size_t ws_size,
                              hipStream_t stream) {
    const float* x   = (const float*)d_in[0];
    const int*   ei  = (const int*)d_in[1];
    const float* W   = (const float*)d_in[2];
    const float* b   = (const float*)d_in[3];
    float*       out = (float*)d_out;

    const int N = in_sizes[0] / D;   // 50000
    const int E = in_sizes[1] / 2;   // 1.6M
    const int* rows = ei;
    const int* cols = ei + E;
    const int NB = (N + RPB - 1) / RPB;        // 196
    const int NT = (E + TILE - 1) / TILE;      // 391
    const int CAP  = (((2 * E) / NB) + 63) / 64 * 64;  // 16384 (uints)
    const int CAPC = CAP;                              // 16384 (bytes)

    // ws layout
    char* p = (char*)d_ws;
    size_t off = 0;
    unsigned short* xlb   = (unsigned short*)(p + off); off += (size_t)N * D * 2;
    unsigned short* wtb   = (unsigned short*)(p + off); off += (size_t)D * D * 2;
    float*          dis   = (float*)(p + off);          off += (size_t)N * 4;
    int*            bcur  = (int*)(p + off);            off += (size_t)MAXB * 4;
    int*            bcurC = (int*)(p + off);            off += (size_t)MAXB * 4;
    int*            begN  = (int*)(p + off);            off += (size_t)N * 4;
    int*            endN  = (int*)(p + off);            off += (size_t)N * 4;
    unsigned*       ebuf  = (unsigned*)(p + off);       off += (size_t)NB * CAP * 4;
    unsigned short* ecol  = (unsigned short*)(p + off); off += (size_t)NB * CAP * 2;
    unsigned char*  cebuf = (unsigned char*)(p + off);  off += (size_t)NB * CAPC;

    const int gN = (N + 255) / 256;
    const int gE = (E + 255) / 256;

    if (N <= 65536 && NB <= MAXB && CAP <= SPLIT_CAP && ws_size >= off) {
        k_prep  <<<(D * D + 255) / 256, 256, 0, stream>>>(W, wtb, bcur, bcurC, NB, CAP, CAPC);
        k_bin   <<<NT, BINB, 0, stream>>>(rows, cols, bcur, bcurC, ebuf, cebuf, E, NB, CAP, CAPC);
        k_degdis<<<NB, 256, 0, stream>>>(bcurC, cebuf, dis, N, CAPC);
        k_split <<<NB, 1024, 0, stream>>>(bcur, ebuf, ecol, begN, endN, N, CAP);
        k_gemm  <<<(N + 63) / 64, 256, 0, stream>>>(x, wtb, b, xlb, N);
        k_reduce<<<(N + 3) / 4, 256, 0, stream>>>(begN, endN, ecol, dis, xlb, out, N);
    } else {
        // fallback: R1 atomic scatter path (fp32 xl)
        char* q = (char*)d_ws;
        float* xl   = (float*)q;
        float* disF = (float*)(q + (size_t)N * D * 4);
        int*   cc   = (int*)(q + (size_t)N * D * 4 + (size_t)N * 4);
        k_zero <<<gN, 256, 0, stream>>>(cc, N);
        k_deg  <<<gE, 256, 0, stream>>>(cols, cc, E);
        k_dis  <<<gN, 256, 0, stream>>>(cc, disF, N);
        k_gemmf<<<(N + GEMM_R - 1) / GEMM_R, 128, 0, stream>>>(x, W, b, xl, N);
        k_self <<<((N * D) + 255) / 256, 256, 0, stream>>>(xl, disF, out, N);
        long long st = (long long)E * 64;
        k_scatter<<<(int)((st + 255) / 256), 256, 0, stream>>>(rows, cols, disF, xl, out, E);
    }
}

// Round 14
// 173.290 us; speedup vs baseline: 1.1550x; 1.0246x over previous
//
#include <hip/hip_runtime.h>
#include <hip/hip_bf16.h>

// GCNConv: out[i] = sum_{e: row[e]=i} dis[row]*dis[col]*xl[col] + dis[i]^2*xl[i]
// N=50000, E=1.6M, D=128, fp32 in/out.
//
// R13 -> R14 (consolidation):
//  - k_degdis fused into k_split (same 196-block grid, independent data):
//    -1 launch, degree hist overlaps split's memory phases.
//  - k_bin: scan lanes write cur/curC with excl/exclC -> one fewer barrier
//    + copy loop.
//  - k_reduce/k_gemm untouched (reduce is at its random-gather HBM floor).

#define D     128
#define TILE  4096
#define BINB  1024      // k_bin block size
#define RPB   256       // rows per bucket
#define MAXB  256       // bucket id must fit 8 bits
#define SPLIT_CAP 16384 // LDS sort capacity (= CAP for N=50000/E=1.6M)

typedef short  bf16x8 __attribute__((ext_vector_type(8)));
typedef float  f32x4  __attribute__((ext_vector_type(4)));
typedef unsigned short us4 __attribute__((ext_vector_type(4)));
typedef unsigned short us8 __attribute__((ext_vector_type(8)));

static __device__ __forceinline__ unsigned short f2bf(float f) {
    unsigned u = __float_as_uint(f);
    u = (u + 0x7FFFu + ((u >> 16) & 1u)) >> 16;   // RNE
    return (unsigned short)u;
}
static __device__ __forceinline__ float bf2f(unsigned short s) {
    return __uint_as_float(((unsigned)s) << 16);
}

// --- init: bcur[b]=b*CAP, bcurC[b]=b*CAPC, wtb = bf16(W^T) ---------------
__global__ __launch_bounds__(256) void k_prep(const float* __restrict__ W,
                                              unsigned short* __restrict__ wtb,
                                              int* __restrict__ bcur,
                                              int* __restrict__ bcurC,
                                              int NB, int CAP, int CAPC) {
    int i = blockIdx.x * 256 + threadIdx.x;
    if (i < NB) { bcur[i] = i * CAP; bcurC[i] = i * CAPC; }
    if (i < D * D) {
        int n = i >> 7, k = i & 127;
        wtb[n * 128 + k] = f2bf(W[k * 128 + n]);
    }
}

// --- bin: in-LDS dual sort (row-key + col-key), coalesced region writes --
__global__ __launch_bounds__(BINB) void k_bin(const int* __restrict__ rows,
                                              const int* __restrict__ cols,
                                              int* __restrict__ bcur,
                                              int* __restrict__ bcurC,
                                              unsigned* __restrict__ ebuf,
                                              unsigned char* __restrict__ cebuf,
                                              int E, int NB, int CAP, int CAPC) {
    __shared__ unsigned sorted[TILE];          // 16 KB
    __shared__ unsigned short sortedC[TILE];   // 8 KB
    __shared__ int lcnt[MAXB], lbase[MAXB], excl[MAXB], cur[MAXB];
    __shared__ int lcntC[MAXB], lbaseC[MAXB], exclC[MAXB], curC[MAXB];
    const int t = threadIdx.x;
    const int base = blockIdx.x * TILE;
    int m = E - base; if (m > TILE) m = TILE;

    unsigned p[TILE / BINB];
    unsigned short q[TILE / BINB];
    #pragma unroll
    for (int it = 0; it < TILE / BINB; ++it) {
        int i = it * BINB + t;
        if (i < m) {
            unsigned r = (unsigned)rows[base + i];
            unsigned c = (unsigned)cols[base + i];
            p[it] = c | ((r & 255u) << 16) | ((r >> 8) << 24);
            q[it] = (unsigned short)c;           // bucket = c>>8, local = c&255
        }
    }
    for (int b = t; b < MAXB; b += BINB) { lcnt[b] = 0; lcntC[b] = 0; }
    __syncthreads();
    #pragma unroll
    for (int it = 0; it < TILE / BINB; ++it) {
        int i = it * BINB + t;
        if (i < m) {
            atomicAdd(&lcnt[p[it] >> 24], 1);
            atomicAdd(&lcntC[q[it] >> 8], 1);
        }
    }
    __syncthreads();
    // wave 0: row scan; wave 1: col scan (shfl ladders); write excl AND cur
    if (t < 64) {
        int b4 = t * 4;
        int v0 = lcnt[b4], v1 = lcnt[b4+1], v2 = lcnt[b4+2], v3 = lcnt[b4+3];
        int s = v0+v1+v2+v3, inc = s;
        #pragma unroll
        for (int off = 1; off < 64; off <<= 1) { int o = __shfl_up(inc, off); if (t >= off) inc += o; }
        int ex = inc - s;
        excl[b4] = ex;          cur[b4]   = ex;
        excl[b4+1] = ex+v0;     cur[b4+1] = ex+v0;
        excl[b4+2] = ex+v0+v1;  cur[b4+2] = ex+v0+v1;
        excl[b4+3] = ex+v0+v1+v2; cur[b4+3] = ex+v0+v1+v2;
    } else if (t < 128) {
        int l = t - 64, b4 = l * 4;
        int v0 = lcntC[b4], v1 = lcntC[b4+1], v2 = lcntC[b4+2], v3 = lcntC[b4+3];
        int s = v0+v1+v2+v3, inc = s;
        #pragma unroll
        for (int off = 1; off < 64; off <<= 1) { int o = __shfl_up(inc, off); if (l >= off) inc += o; }
        int ex = inc - s;
        exclC[b4] = ex;           curC[b4]   = ex;
        exclC[b4+1] = ex+v0;      curC[b4+1] = ex+v0;
        exclC[b4+2] = ex+v0+v1;   curC[b4+2] = ex+v0+v1;
        exclC[b4+3] = ex+v0+v1+v2; curC[b4+3] = ex+v0+v1+v2;
    }
    for (int b = t; b < NB; b += BINB) {     // reserve global regions
        int c = lcnt[b];
        lbase[b] = c ? atomicAdd(&bcur[b], c) : 0;
        int cc = lcntC[b];
        lbaseC[b] = cc ? atomicAdd(&bcurC[b], cc) : 0;
    }
    __syncthreads();
    #pragma unroll
    for (int it = 0; it < TILE / BINB; ++it) {  // scatter into LDS (random: free)
        int i = it * BINB + t;
        if (i < m) {
            int pos  = atomicAdd(&cur[p[it] >> 24], 1);
            sorted[pos] = p[it];
            int posC = atomicAdd(&curC[q[it] >> 8], 1);
            sortedC[posC] = q[it];
        }
    }
    __syncthreads();
    #pragma unroll
    for (int it = 0; it < TILE / BINB; ++it) {  // positional coalesced writes
        int i = it * BINB + t;
        if (i < m) {
            unsigned pp = sorted[i];
            int bk = pp >> 24;
            int g  = lbase[bk] + i - excl[bk];
            if (g < (bk + 1) * CAP) ebuf[g] = pp & 0xFFFFFFu;
            unsigned short qq = sortedC[i];
            int bc = qq >> 8;
            int gc = lbaseC[bc] + i - exclC[bc];
            if (gc < (bc + 1) * CAPC) cebuf[gc] = (unsigned char)(qq & 255u);
        }
    }
}

// --- split (row counting sort -> ecol/begN/endN) + degree/dis fused ------
__global__ __launch_bounds__(1024) void k_split(const int* __restrict__ bcur,
                                                const int* __restrict__ bcurC,
                                                const unsigned* __restrict__ ebuf,
                                                const unsigned char* __restrict__ cebuf,
                                                unsigned short* __restrict__ ecol,
                                                int* __restrict__ begN,
                                                int* __restrict__ endN,
                                                float* __restrict__ dis,
                                                int N, int CAP, int CAPC) {
    __shared__ unsigned short sorted[SPLIT_CAP];    // 32 KB
    __shared__ int cnt[RPB];
    __shared__ int excl[RPB];
    __shared__ int cur[RPB];
    __shared__ int cntD[RPB];
    const int b = blockIdx.x, t = threadIdx.x;
    const int base = b * CAP;
    int m = bcur[b] - base; if (m > CAP) m = CAP;
    const int baseC = b * CAPC;
    int mD = bcurC[b] - baseC; if (mD > CAPC) mD = CAPC;
    if (t < RPB) { cnt[t] = 0; cntD[t] = 0; }
    __syncthreads();
    // degree hist (col bucket b) — word-packed cebuf reads
    const unsigned* cw = (const unsigned*)(cebuf + baseC);   // base 4-aligned
    int nw = mD >> 2;
    for (int i = t; i < nw; i += 1024) {
        unsigned u = cw[i];
        atomicAdd(&cntD[u & 255u], 1);
        atomicAdd(&cntD[(u >> 8) & 255u], 1);
        atomicAdd(&cntD[(u >> 16) & 255u], 1);
        atomicAdd(&cntD[u >> 24], 1);
    }
    if (t < (mD & 3)) atomicAdd(&cntD[cebuf[baseC + nw * 4 + t]], 1);
    // row-key counting
    for (int i = t; i < m; i += 1024)
        atomicAdd(&cnt[(ebuf[base + i] >> 16) & 255], 1);
    __syncthreads();
    const int row0 = b * RPB;
    if (t < RPB && row0 + t < N)
        dis[row0 + t] = rsqrtf((float)(cntD[t] + 1));
    if (t < 64) {                                   // wave scan of 256 keys
        int b4 = t * 4;
        int v0 = cnt[b4], v1 = cnt[b4+1], v2 = cnt[b4+2], v3 = cnt[b4+3];
        int s = v0+v1+v2+v3, inc = s;
        #pragma unroll
        for (int off = 1; off < 64; off <<= 1) { int o = __shfl_up(inc, off); if (t >= off) inc += o; }
        int ex = inc - s;
        excl[b4] = ex;            cur[b4]   = ex;
        excl[b4+1] = ex+v0;       cur[b4+1] = ex+v0;
        excl[b4+2] = ex+v0+v1;    cur[b4+2] = ex+v0+v1;
        excl[b4+3] = ex+v0+v1+v2; cur[b4+3] = ex+v0+v1+v2;
    }
    __syncthreads();
    if (t < RPB && row0 + t < N) {
        begN[row0 + t] = base + excl[t];
        endN[row0 + t] = base + excl[t] + cnt[t];
    }
    for (int i = t; i < m; i += 1024) {
        unsigned p = ebuf[base + i];
        int pos = atomicAdd(&cur[(p >> 16) & 255], 1);
        sorted[pos] = (unsigned short)(p & 0xFFFFu);   // random scatter in LDS
    }
    __syncthreads();
    for (int i = t; i < m; i += 1024)
        ecol[base + i] = sorted[i];                     // linear coalesced write
}

// --- MFMA bf16 GEMM: xlb = bf16(x @ W + b), 64x128 tile per block --------
__global__ __launch_bounds__(256) void k_gemm(const float* __restrict__ x,
                                              const unsigned short* __restrict__ wtb,
                                              const float* __restrict__ bia,
                                              unsigned short* __restrict__ xlb,
                                              int N) {
    __shared__ unsigned short wt[128][136];   // W^T bf16, pad 8 -> 16B-aligned rows
    __shared__ unsigned short xs[64][136];    // x tile bf16
    const int t = threadIdx.x;
    const int row0 = blockIdx.x * 64;

    #pragma unroll
    for (int i = 0; i < 8; ++i) {             // W^T: 2048 ushort8, ds_write_b128
        int j = i * 256 + t;
        int n = j >> 4, k8 = j & 15;
        us8 v = *(const us8*)&wtb[j * 8];
        *(us8*)&wt[n][k8 * 8] = v;
    }
    #pragma unroll
    for (int i = 0; i < 8; ++i) {             // x: 2048 float4 -> ushort4
        int j = i * 256 + t;
        int r = j >> 5, c4 = j & 31;
        int gr = row0 + r;
        us4 o = (us4){0, 0, 0, 0};
        if (gr < N) {
            float4 v = *(const float4*)&x[(size_t)gr * D + c4 * 4];
            o = (us4){f2bf(v.x), f2bf(v.y), f2bf(v.z), f2bf(v.w)};
        }
        *(us4*)&xs[r][c4 * 4] = o;
    }
    __syncthreads();

    const int w  = t >> 6, l = t & 63;
    const int m0 = w * 16;
    const int lm = l & 15, lq = l >> 4;

    f32x4 acc[8];
    #pragma unroll
    for (int nt = 0; nt < 8; ++nt) acc[nt] = (f32x4){0.f, 0.f, 0.f, 0.f};

    #pragma unroll
    for (int kk = 0; kk < 4; ++kk) {
        const int kof = kk * 32 + lq * 8;
        bf16x8 a = *(const bf16x8*)&xs[m0 + lm][kof];
        #pragma unroll
        for (int nt = 0; nt < 8; ++nt) {
            bf16x8 bb = *(const bf16x8*)&wt[nt * 16 + lm][kof];
            acc[nt] = __builtin_amdgcn_mfma_f32_16x16x32_bf16(a, bb, acc[nt], 0, 0, 0);
        }
    }

    #pragma unroll
    for (int nt = 0; nt < 8; ++nt) {
        const int col = nt * 16 + lm;
        const float bc = bia[col];
        #pragma unroll
        for (int r = 0; r < 4; ++r) {
            int grow = row0 + m0 + lq * 4 + r;
            if (grow < N) xlb[(size_t)grow * D + col] = f2bf(acc[nt][r] + bc);
        }
    }
}

// --- wave-per-node gather-reduce (no LDS, no barriers) -------------------
__global__ __launch_bounds__(256) void k_reduce(const int* __restrict__ begN,
                                                const int* __restrict__ endN,
                                                const unsigned short* __restrict__ ecol,
                                                const float* __restrict__ dis,
                                                const unsigned short* __restrict__ xlb,
                                                float* __restrict__ out, int N) {
    const int wave = threadIdx.x >> 6;
    const int lane = threadIdx.x & 63;
    const int i = blockIdx.x * 4 + wave;
    if (i >= N) return;
    const float di = dis[i];

    // self loop
    const ushort2 sv = *reinterpret_cast<const ushort2*>(xlb + (size_t)i * D + lane * 2);
    float ax = di * di * bf2f(sv.x);
    float ay = di * di * bf2f(sv.y);

    const int beg = begN[i], end = endN[i];
    for (int base = beg; base < end; base += 64) {
        int m = end - base; if (m > 64) m = 64;
        int   c = 0;
        float n = 0.0f;
        if (lane < m) {
            c = ecol[base + lane];
            n = di * dis[c];
        }
        for (int j = 0; j < m; j += 8) {
            float vx[8], vy[8], nn[8];
            #pragma unroll
            for (int u = 0; u < 8; ++u) {          // 8 independent 256B gathers
                int cc = __shfl(c, j + u);         // lanes >= m carry c=0,n=0
                ushort2 s = *reinterpret_cast<const ushort2*>(xlb + (size_t)cc * D + lane * 2);
                vx[u] = bf2f(s.x);
                vy[u] = bf2f(s.y);
                nn[u] = __shfl(n, j + u);
            }
            #pragma unroll
            for (int u = 0; u < 8; ++u) {
                ax = fmaf(nn[u], vx[u], ax);
                ay = fmaf(nn[u], vy[u], ay);
            }
        }
    }
    *reinterpret_cast<float2*>(out + (size_t)i * D + lane * 2) = make_float2(ax, ay);
}

// ======================= fallback (R1 atomic path) =======================
__global__ __launch_bounds__(256) void k_zero(int* __restrict__ p, int n) {
    int i = blockIdx.x * 256 + threadIdx.x;
    if (i < n) p[i] = 0;
}
__global__ __launch_bounds__(256) void k_deg(const int* __restrict__ cols,
                                             int* __restrict__ cntc, int E) {
    int e = blockIdx.x * 256 + threadIdx.x;
    if (e < E) atomicAdd(&cntc[cols[e]], 1);
}
__global__ __launch_bounds__(256) void k_dis(const int* __restrict__ cntc,
                                             float* __restrict__ dis, int N) {
    int i = blockIdx.x * 256 + threadIdx.x;
    if (i < N) dis[i] = rsqrtf((float)(cntc[i] + 1));
}
#define GEMM_R 8
__global__ __launch_bounds__(128) void k_gemmf(const float* __restrict__ x,
                                               const float* __restrict__ W,
                                               const float* __restrict__ b,
                                               float* __restrict__ xl, int N) {
    __shared__ float xs[GEMM_R][D];
    const int c  = threadIdx.x;
    const int r0 = blockIdx.x * GEMM_R;
    #pragma unroll
    for (int r = 0; r < GEMM_R; ++r) {
        int row = r0 + r;
        xs[r][c] = (row < N) ? x[row * D + c] : 0.0f;
    }
    __syncthreads();
    float acc[GEMM_R];
    const float bc = b[c];
    #pragma unroll
    for (int r = 0; r < GEMM_R; ++r) acc[r] = bc;
    for (int k = 0; k < D; k += 4) {
        const float w0 = W[(k + 0) * D + c];
        const float w1 = W[(k + 1) * D + c];
        const float w2 = W[(k + 2) * D + c];
        const float w3 = W[(k + 3) * D + c];
        #pragma unroll
        for (int r = 0; r < GEMM_R; ++r) {
            const float4 xv = *reinterpret_cast<const float4*>(&xs[r][k]);
            acc[r] = fmaf(xv.x, w0, acc[r]);
            acc[r] = fmaf(xv.y, w1, acc[r]);
            acc[r] = fmaf(xv.z, w2, acc[r]);
            acc[r] = fmaf(xv.w, w3, acc[r]);
        }
    }
    #pragma unroll
    for (int r = 0; r < GEMM_R; ++r) {
        int row = r0 + r;
        if (row < N) xl[row * D + c] = acc[r];
    }
}
__global__ __launch_bounds__(256) void k_self(const float* __restrict__ xl,
                                              const float* __restrict__ dis,
                                              float* __restrict__ out, int N) {
    int gid = blockIdx.x * 256 + threadIdx.x;
    int i = gid >> 7;
    if (i < N) {
        float d = dis[i];
        out[gid] = d * d * xl[gid];
    }
}
__global__ __launch_bounds__(256) void k_scatter(const int* __restrict__ rows,
                                                 const int* __restrict__ cols,
                                                 const float* __restrict__ dis,
                                                 const float* __restrict__ xl,
                                                 float* __restrict__ out, int E) {
    long long gid = (long long)blockIdx.x * 256 + threadIdx.x;
    int e    = (int)(gid >> 6);
    int lane = (int)(gid & 63);
    if (e >= E) return;
    const int row = rows[e];
    const int col = cols[e];
    const float nrm = dis[row] * dis[col];
    atomicAdd(&out[row * D + lane],      nrm * xl[col * D + lane]);
    atomicAdd(&out[row * D + 64 + lane], nrm * xl[col * D + 64 + lane]);
}

// ======================= launch ==========================================
extern "C" void kernel_launch(void* const* d_in, const int* in_sizes, int n_in,
                              void* d_out, int out_size, void* d_ws, size_t ws_size,
                              hipStream_t stream) {
    const float* x   = (const float*)d_in[0];
    const int*   ei  = (const int*)d_in[1];
    const float* W   = (const float*)d_in[2];
    const float* b   = (const float*)d_in[3];
    float*       out = (float*)d_out;

    const int N = in_sizes[0] / D;   // 50000
    const int E = in_sizes[1] / 2;   // 1.6M
    const int* rows = ei;
    const int* cols = ei + E;
    const int NB = (N + RPB - 1) / RPB;        // 196
    const int NT = (E + TILE - 1) / TILE;      // 391
    const int CAP  = (((2 * E) / NB) + 63) / 64 * 64;  // 16384 (uints)
    const int CAPC = CAP;                              // 16384 (bytes)

    // ws layout
    char* p = (char*)d_ws;
    size_t off = 0;
    unsigned short* xlb   = (unsigned short*)(p + off); off += (size_t)N * D * 2;
    unsigned short* wtb   = (unsigned short*)(p + off); off += (size_t)D * D * 2;
    float*          dis   = (float*)(p + off);          off += (size_t)N * 4;
    int*            bcur  = (int*)(p + off);            off += (size_t)MAXB * 4;
    int*            bcurC = (int*)(p + off);            off += (size_t)MAXB * 4;
    int*            begN  = (int*)(p + off);            off += (size_t)N * 4;
    int*            endN  = (int*)(p + off);            off += (size_t)N * 4;
    unsigned*       ebuf  = (unsigned*)(p + off);       off += (size_t)NB * CAP * 4;
    unsigned short* ecol  = (unsigned short*)(p + off); off += (size_t)NB * CAP * 2;
    unsigned char*  cebuf = (unsigned char*)(p + off);  off += (size_t)NB * CAPC;

    const int gN = (N + 255) / 256;
    const int gE = (E + 255) / 256;

    if (N <= 65536 && NB <= MAXB && CAP <= SPLIT_CAP && ws_size >= off) {
        k_prep  <<<(D * D + 255) / 256, 256, 0, stream>>>(W, wtb, bcur, bcurC, NB, CAP, CAPC);
        k_bin   <<<NT, BINB, 0, stream>>>(rows, cols, bcur, bcurC, ebuf, cebuf, E, NB, CAP, CAPC);
        k_split <<<NB, 1024, 0, stream>>>(bcur, bcurC, ebuf, cebuf, ecol, begN, endN, dis, N, CAP, CAPC);
        k_gemm  <<<(N + 63) / 64, 256, 0, stream>>>(x, wtb, b, xlb, N);
        k_reduce<<<(N + 3) / 4, 256, 0, stream>>>(begN, endN, ecol, dis, xlb, out, N);
    } else {
        // fallback: R1 atomic scatter path (fp32 xl)
        char* q = (char*)d_ws;
        float* xl   = (float*)q;
        float* disF = (float*)(q + (size_t)N * D * 4);
        int*   cc   = (int*)(q + (size_t)N * D * 4 + (size_t)N * 4);
        k_zero <<<gN, 256, 0, stream>>>(cc, N);
        k_deg  <<<gE, 256, 0, stream>>>(cols, cc, E);
        k_dis  <<<gN, 256, 0, stream>>>(cc, disF, N);
        k_gemmf<<<(N + GEMM_R - 1) / GEMM_R, 128, 0, stream>>>(x, W, b, xl, N);
        k_self <<<((N * D) + 255) / 256, 256, 0, stream>>>(xl, disF, out, N);
        long long st = (long long)E * 64;
        k_scatter<<<(int)((st + 255) / 256), 256, 0, stream>>>(rows, cols, disF, xl, out, E);
    }
}

// Round 15
// 161.095 us; speedup vs baseline: 1.2424x; 1.0757x over previous
//
#include <hip/hip_runtime.h>
#include <hip/hip_bf16.h>

// GCNConv: out[i] = sum_{e: row[e]=i} dis[row]*dis[col]*xl[col] + dis[i]^2*xl[i]
// N=50000, E=1.6M, D=128, fp32 in/out.
//
// R14 -> R15: k_bin+k_split ~100us, both sub-visible. Parallelism fixes:
//  - RPB 256->128 (NB=391): k_split 2x blocks, half per-block serial work.
//    Packing: col:16 | rowlocal:7 | bucket:9 (MAXB 512).
//  - k_gemm fused into k_bin (k_binjoint, block-specialized): gemm overlaps
//    binning, -1 launch. LDS union 64KB, 2 blocks/CU.

#define D     128
#define TILE  8192
#define BINB  1024      // k_binjoint block size
#define RPB   128       // rows per bucket
#define MAXB  512       // bucket id fits 9 bits
#define SPLIT_CAP 8192  // LDS sort capacity (= CAP for N=50000/E=1.6M)

typedef short  bf16x8 __attribute__((ext_vector_type(8)));
typedef float  f32x4  __attribute__((ext_vector_type(4)));
typedef unsigned short us4 __attribute__((ext_vector_type(4)));
typedef unsigned short us8 __attribute__((ext_vector_type(8)));

static __device__ __forceinline__ unsigned short f2bf(float f) {
    unsigned u = __float_as_uint(f);
    u = (u + 0x7FFFu + ((u >> 16) & 1u)) >> 16;   // RNE
    return (unsigned short)u;
}
static __device__ __forceinline__ float bf2f(unsigned short s) {
    return __uint_as_float(((unsigned)s) << 16);
}

// --- init: bcur[b]=b*CAP, bcurC[b]=b*CAPC, wtb = bf16(W^T) ---------------
__global__ __launch_bounds__(256) void k_prep(const float* __restrict__ W,
                                              unsigned short* __restrict__ wtb,
                                              int* __restrict__ bcur,
                                              int* __restrict__ bcurC,
                                              int NB, int CAP, int CAPC) {
    int i = blockIdx.x * 256 + threadIdx.x;
    if (i < NB) { bcur[i] = i * CAP; bcurC[i] = i * CAPC; }
    if (i < D * D) {
        int n = i >> 7, k = i & 127;
        wtb[n * 128 + k] = f2bf(W[k * 128 + n]);
    }
}

// --- fused: blocks <NT bin edges; blocks >=NT do MFMA gemm ---------------
__global__ __launch_bounds__(1024) void k_binjoint(
        const int* __restrict__ rows, const int* __restrict__ cols,
        int* __restrict__ bcur, int* __restrict__ bcurC,
        unsigned* __restrict__ ebuf, unsigned char* __restrict__ cebuf,
        const float* __restrict__ x, const unsigned short* __restrict__ wtb,
        const float* __restrict__ bia, unsigned short* __restrict__ xlb,
        int E, int N, int NB, int CAP, int CAPC, int NT) {
    __shared__ __align__(16) unsigned char smem[65536];
    const int t = threadIdx.x;

    if ((int)blockIdx.x >= NT) {
        // ---------------- gemm path: 64x128 tile, waves 0-3 compute ------
        unsigned short (*wt)[136] = (unsigned short (*)[136])smem;            // 34816 B
        unsigned short (*xs)[136] = (unsigned short (*)[136])(smem + 34816);  // 17408 B
        const int row0 = ((int)blockIdx.x - NT) * 64;
        #pragma unroll
        for (int i = 0; i < 2; ++i) {         // W^T: 2048 ushort8 chunks
            int j = i * 1024 + t;
            int n = j >> 4, k8 = j & 15;
            us8 v = *(const us8*)&wtb[j * 8];
            *(us8*)&wt[n][k8 * 8] = v;
        }
        #pragma unroll
        for (int i = 0; i < 2; ++i) {         // x: 2048 float4 -> ushort4
            int j = i * 1024 + t;
            int r = j >> 5, c4 = j & 31;
            int gr = row0 + r;
            us4 o = (us4){0, 0, 0, 0};
            if (gr < N) {
                float4 v = *(const float4*)&x[(size_t)gr * D + c4 * 4];
                o = (us4){f2bf(v.x), f2bf(v.y), f2bf(v.z), f2bf(v.w)};
            }
            *(us4*)&xs[r][c4 * 4] = o;
        }
        __syncthreads();
        if (t < 256) {
            const int w  = t >> 6, l = t & 63;
            const int m0 = w * 16;
            const int lm = l & 15, lq = l >> 4;
            f32x4 acc[8];
            #pragma unroll
            for (int nt = 0; nt < 8; ++nt) acc[nt] = (f32x4){0.f, 0.f, 0.f, 0.f};
            #pragma unroll
            for (int kk = 0; kk < 4; ++kk) {
                const int kof = kk * 32 + lq * 8;
                bf16x8 a = *(const bf16x8*)&xs[m0 + lm][kof];
                #pragma unroll
                for (int nt = 0; nt < 8; ++nt) {
                    bf16x8 bb = *(const bf16x8*)&wt[nt * 16 + lm][kof];
                    acc[nt] = __builtin_amdgcn_mfma_f32_16x16x32_bf16(a, bb, acc[nt], 0, 0, 0);
                }
            }
            #pragma unroll
            for (int nt = 0; nt < 8; ++nt) {
                const int col = nt * 16 + lm;
                const float bc = bia[col];
                #pragma unroll
                for (int r = 0; r < 4; ++r) {
                    int grow = row0 + m0 + lq * 4 + r;
                    if (grow < N) xlb[(size_t)grow * D + col] = f2bf(acc[nt][r] + bc);
                }
            }
        }
        return;
    }

    // ---------------- bin path: in-LDS dual sort, coalesced writes -------
    unsigned*       sorted  = (unsigned*)smem;                  // 32 KB
    unsigned short* sortedC = (unsigned short*)(smem + 32768);  // 16 KB
    int* lcnt   = (int*)(smem + 49152);
    int* lbase  = lcnt + 512;
    int* excl   = lcnt + 1024;
    int* cur    = lcnt + 1536;
    int* lcntC  = lcnt + 2048;
    int* lbaseC = lcnt + 2560;
    int* exclC  = lcnt + 3072;
    int* curC   = lcnt + 3584;                                  // ends at 64 KB

    const int base = blockIdx.x * TILE;
    int m = E - base; if (m > TILE) m = TILE;

    unsigned p[TILE / BINB];
    unsigned short q[TILE / BINB];
    #pragma unroll
    for (int it = 0; it < TILE / BINB; ++it) {
        int i = it * BINB + t;
        if (i < m) {
            unsigned r = (unsigned)rows[base + i];
            unsigned c = (unsigned)cols[base + i];
            p[it] = c | ((r & 127u) << 16) | ((r >> 7) << 23);
            q[it] = (unsigned short)c;           // bucket = c>>7, local = c&127
        }
    }
    if (t < 512) { lcnt[t] = 0; lcntC[t] = 0; }
    __syncthreads();
    #pragma unroll
    for (int it = 0; it < TILE / BINB; ++it) {
        int i = it * BINB + t;
        if (i < m) {
            atomicAdd(&lcnt[p[it] >> 23], 1);
            atomicAdd(&lcntC[q[it] >> 7], 1);
        }
    }
    __syncthreads();
    // wave 0: row scan (8 keys/lane); wave 1: col scan; write excl AND cur
    if (t < 64) {
        int k0 = t * 8, v[8], s = 0;
        #pragma unroll
        for (int u = 0; u < 8; ++u) { v[u] = lcnt[k0 + u]; s += v[u]; }
        int inc = s;
        #pragma unroll
        for (int off = 1; off < 64; off <<= 1) { int o = __shfl_up(inc, off); if (t >= off) inc += o; }
        int run = inc - s;
        #pragma unroll
        for (int u = 0; u < 8; ++u) { excl[k0 + u] = run; cur[k0 + u] = run; run += v[u]; }
    } else if (t < 128) {
        int l = t - 64, k0 = l * 8, v[8], s = 0;
        #pragma unroll
        for (int u = 0; u < 8; ++u) { v[u] = lcntC[k0 + u]; s += v[u]; }
        int inc = s;
        #pragma unroll
        for (int off = 1; off < 64; off <<= 1) { int o = __shfl_up(inc, off); if (l >= off) inc += o; }
        int run = inc - s;
        #pragma unroll
        for (int u = 0; u < 8; ++u) { exclC[k0 + u] = run; curC[k0 + u] = run; run += v[u]; }
    }
    for (int b = t; b < NB; b += BINB) {     // reserve global regions
        int c = lcnt[b];
        lbase[b] = c ? atomicAdd(&bcur[b], c) : 0;
        int cc = lcntC[b];
        lbaseC[b] = cc ? atomicAdd(&bcurC[b], cc) : 0;
    }
    __syncthreads();
    #pragma unroll
    for (int it = 0; it < TILE / BINB; ++it) {  // scatter into LDS (random: free)
        int i = it * BINB + t;
        if (i < m) {
            int pos  = atomicAdd(&cur[p[it] >> 23], 1);
            sorted[pos] = p[it];
            int posC = atomicAdd(&curC[q[it] >> 7], 1);
            sortedC[posC] = q[it];
        }
    }
    __syncthreads();
    #pragma unroll
    for (int it = 0; it < TILE / BINB; ++it) {  // positional coalesced writes
        int i = it * BINB + t;
        if (i < m) {
            unsigned pp = sorted[i];
            int bk = pp >> 23;
            int g  = lbase[bk] + i - excl[bk];
            if (g < (bk + 1) * CAP) ebuf[g] = pp & 0x7FFFFFu;   // col | rl<<16
            unsigned short qq = sortedC[i];
            int bc = qq >> 7;
            int gc = lbaseC[bc] + i - exclC[bc];
            if (gc < (bc + 1) * CAPC) cebuf[gc] = (unsigned char)(qq & 127u);
        }
    }
}

// --- split (row counting sort -> ecol/begN/endN) + degree/dis fused ------
__global__ __launch_bounds__(1024) void k_split(const int* __restrict__ bcur,
                                                const int* __restrict__ bcurC,
                                                const unsigned* __restrict__ ebuf,
                                                const unsigned char* __restrict__ cebuf,
                                                unsigned short* __restrict__ ecol,
                                                int* __restrict__ begN,
                                                int* __restrict__ endN,
                                                float* __restrict__ dis,
                                                int N, int CAP, int CAPC) {
    __shared__ unsigned short sorted[SPLIT_CAP];    // 16 KB
    __shared__ int cnt[RPB];
    __shared__ int excl[RPB];
    __shared__ int cur[RPB];
    __shared__ int cntD[RPB];
    const int b = blockIdx.x, t = threadIdx.x;
    const int base = b * CAP;
    int m = bcur[b] - base; if (m > CAP) m = CAP;
    const int baseC = b * CAPC;
    int mD = bcurC[b] - baseC; if (mD > CAPC) mD = CAPC;
    if (t < RPB) { cnt[t] = 0; cntD[t] = 0; }
    __syncthreads();
    // degree hist (col bucket b) — word-packed cebuf reads
    const unsigned* cw = (const unsigned*)(cebuf + baseC);   // base 4-aligned
    int nw = mD >> 2;
    for (int i = t; i < nw; i += 1024) {
        unsigned u = cw[i];
        atomicAdd(&cntD[u & 255u], 1);
        atomicAdd(&cntD[(u >> 8) & 255u], 1);
        atomicAdd(&cntD[(u >> 16) & 255u], 1);
        atomicAdd(&cntD[u >> 24], 1);
    }
    if (t < (mD & 3)) atomicAdd(&cntD[cebuf[baseC + nw * 4 + t]], 1);
    // row-key counting
    for (int i = t; i < m; i += 1024)
        atomicAdd(&cnt[(ebuf[base + i] >> 16) & 127], 1);
    __syncthreads();
    const int row0 = b * RPB;
    if (t < RPB && row0 + t < N)
        dis[row0 + t] = rsqrtf((float)(cntD[t] + 1));
    if (t < 64) {                                   // wave scan of 128 keys
        int v0 = cnt[2 * t], v1 = cnt[2 * t + 1];
        int s = v0 + v1, inc = s;
        #pragma unroll
        for (int off = 1; off < 64; off <<= 1) { int o = __shfl_up(inc, off); if (t >= off) inc += o; }
        int ex = inc - s;
        excl[2 * t] = ex;          cur[2 * t] = ex;
        excl[2 * t + 1] = ex + v0; cur[2 * t + 1] = ex + v0;
    }
    __syncthreads();
    if (t < RPB && row0 + t < N) {
        begN[row0 + t] = base + excl[t];
        endN[row0 + t] = base + excl[t] + cnt[t];
    }
    for (int i = t; i < m; i += 1024) {
        unsigned p = ebuf[base + i];
        int pos = atomicAdd(&cur[(p >> 16) & 127], 1);
        sorted[pos] = (unsigned short)(p & 0xFFFFu);   // random scatter in LDS
    }
    __syncthreads();
    for (int i = t; i < m; i += 1024)
        ecol[base + i] = sorted[i];                     // linear coalesced write
}

// --- wave-per-node gather-reduce (no LDS, no barriers) -------------------
__global__ __launch_bounds__(256) void k_reduce(const int* __restrict__ begN,
                                                const int* __restrict__ endN,
                                                const unsigned short* __restrict__ ecol,
                                                const float* __restrict__ dis,
                                                const unsigned short* __restrict__ xlb,
                                                float* __restrict__ out, int N) {
    const int wave = threadIdx.x >> 6;
    const int lane = threadIdx.x & 63;
    const int i = blockIdx.x * 4 + wave;
    if (i >= N) return;
    const float di = dis[i];

    // self loop
    const ushort2 sv = *reinterpret_cast<const ushort2*>(xlb + (size_t)i * D + lane * 2);
    float ax = di * di * bf2f(sv.x);
    float ay = di * di * bf2f(sv.y);

    const int beg = begN[i], end = endN[i];
    for (int base = beg; base < end; base += 64) {
        int m = end - base; if (m > 64) m = 64;
        int   c = 0;
        float n = 0.0f;
        if (lane < m) {
            c = ecol[base + lane];
            n = di * dis[c];
        }
        for (int j = 0; j < m; j += 8) {
            float vx[8], vy[8], nn[8];
            #pragma unroll
            for (int u = 0; u < 8; ++u) {          // 8 independent 256B gathers
                int cc = __shfl(c, j + u);         // lanes >= m carry c=0,n=0
                ushort2 s = *reinterpret_cast<const ushort2*>(xlb + (size_t)cc * D + lane * 2);
                vx[u] = bf2f(s.x);
                vy[u] = bf2f(s.y);
                nn[u] = __shfl(n, j + u);
            }
            #pragma unroll
            for (int u = 0; u < 8; ++u) {
                ax = fmaf(nn[u], vx[u], ax);
                ay = fmaf(nn[u], vy[u], ay);
            }
        }
    }
    *reinterpret_cast<float2*>(out + (size_t)i * D + lane * 2) = make_float2(ax, ay);
}

// ======================= fallback (R1 atomic path) =======================
__global__ __launch_bounds__(256) void k_zero(int* __restrict__ p, int n) {
    int i = blockIdx.x * 256 + threadIdx.x;
    if (i < n) p[i] = 0;
}
__global__ __launch_bounds__(256) void k_deg(const int* __restrict__ cols,
                                             int* __restrict__ cntc, int E) {
    int e = blockIdx.x * 256 + threadIdx.x;
    if (e < E) atomicAdd(&cntc[cols[e]], 1);
}
__global__ __launch_bounds__(256) void k_dis(const int* __restrict__ cntc,
                                             float* __restrict__ dis, int N) {
    int i = blockIdx.x * 256 + threadIdx.x;
    if (i < N) dis[i] = rsqrtf((float)(cntc[i] + 1));
}
#define GEMM_R 8
__global__ __launch_bounds__(128) void k_gemmf(const float* __restrict__ x,
                                               const float* __restrict__ W,
                                               const float* __restrict__ b,
                                               float* __restrict__ xl, int N) {
    __shared__ float xs[GEMM_R][D];
    const int c  = threadIdx.x;
    const int r0 = blockIdx.x * GEMM_R;
    #pragma unroll
    for (int r = 0; r < GEMM_R; ++r) {
        int row = r0 + r;
        xs[r][c] = (row < N) ? x[row * D + c] : 0.0f;
    }
    __syncthreads();
    float acc[GEMM_R];
    const float bc = b[c];
    #pragma unroll
    for (int r = 0; r < GEMM_R; ++r) acc[r] = bc;
    for (int k = 0; k < D; k += 4) {
        const float w0 = W[(k + 0) * D + c];
        const float w1 = W[(k + 1) * D + c];
        const float w2 = W[(k + 2) * D + c];
        const float w3 = W[(k + 3) * D + c];
        #pragma unroll
        for (int r = 0; r < GEMM_R; ++r) {
            const float4 xv = *reinterpret_cast<const float4*>(&xs[r][k]);
            acc[r] = fmaf(xv.x, w0, acc[r]);
            acc[r] = fmaf(xv.y, w1, acc[r]);
            acc[r] = fmaf(xv.z, w2, acc[r]);
            acc[r] = fmaf(xv.w, w3, acc[r]);
        }
    }
    #pragma unroll
    for (int r = 0; r < GEMM_R; ++r) {
        int row = r0 + r;
        if (row < N) xl[row * D + c] = acc[r];
    }
}
__global__ __launch_bounds__(256) void k_self(const float* __restrict__ xl,
                                              const float* __restrict__ dis,
                                              float* __restrict__ out, int N) {
    int gid = blockIdx.x * 256 + threadIdx.x;
    int i = gid >> 7;
    if (i < N) {
        float d = dis[i];
        out[gid] = d * d * xl[gid];
    }
}
__global__ __launch_bounds__(256) void k_scatter(const int* __restrict__ rows,
                                                 const int* __restrict__ cols,
                                                 const float* __restrict__ dis,
                                                 const float* __restrict__ xl,
                                                 float* __restrict__ out, int E) {
    long long gid = (long long)blockIdx.x * 256 + threadIdx.x;
    int e    = (int)(gid >> 6);
    int lane = (int)(gid & 63);
    if (e >= E) return;
    const int row = rows[e];
    const int col = cols[e];
    const float nrm = dis[row] * dis[col];
    atomicAdd(&out[row * D + lane],      nrm * xl[col * D + lane]);
    atomicAdd(&out[row * D + 64 + lane], nrm * xl[col * D + 64 + lane]);
}

// ======================= launch ==========================================
extern "C" void kernel_launch(void* const* d_in, const int* in_sizes, int n_in,
                              void* d_out, int out_size, void* d_ws, size_t ws_size,
                              hipStream_t stream) {
    const float* x   = (const float*)d_in[0];
    const int*   ei  = (const int*)d_in[1];
    const float* W   = (const float*)d_in[2];
    const float* b   = (const float*)d_in[3];
    float*       out = (float*)d_out;

    const int N = in_sizes[0] / D;   // 50000
    const int E = in_sizes[1] / 2;   // 1.6M
    const int* rows = ei;
    const int* cols = ei + E;
    const int NB = (N + RPB - 1) / RPB;        // 391
    const int NT = (E + TILE - 1) / TILE;      // 196
    const int GN = (N + 63) / 64;              // 782 gemm blocks
    const int CAP  = (((2 * E) / NB) + 63) / 64 * 64;  // 8192 (uints)
    const int CAPC = CAP;                              // 8192 (bytes)

    // ws layout
    char* p = (char*)d_ws;
    size_t off = 0;
    unsigned short* xlb   = (unsigned short*)(p + off); off += (size_t)N * D * 2;
    unsigned short* wtb   = (unsigned short*)(p + off); off += (size_t)D * D * 2;
    float*          dis   = (float*)(p + off);          off += (size_t)N * 4;
    int*            bcur  = (int*)(p + off);            off += (size_t)MAXB * 4;
    int*            bcurC = (int*)(p + off);            off += (size_t)MAXB * 4;
    int*            begN  = (int*)(p + off);            off += (size_t)N * 4;
    int*            endN  = (int*)(p + off);            off += (size_t)N * 4;
    unsigned*       ebuf  = (unsigned*)(p + off);       off += (size_t)NB * CAP * 4;
    unsigned short* ecol  = (unsigned short*)(p + off); off += (size_t)NB * CAP * 2;
    unsigned char*  cebuf = (unsigned char*)(p + off);  off += (size_t)NB * CAPC;

    const int gN = (N + 255) / 256;
    const int gE = (E + 255) / 256;

    if (N <= 65536 && NB <= MAXB && CAP <= SPLIT_CAP && ws_size >= off) {
        k_prep    <<<(D * D + 255) / 256, 256, 0, stream>>>(W, wtb, bcur, bcurC, NB, CAP, CAPC);
        k_binjoint<<<NT + GN, BINB, 0, stream>>>(rows, cols, bcur, bcurC, ebuf, cebuf,
                                                 x, wtb, b, xlb, E, N, NB, CAP, CAPC, NT);
        k_split   <<<NB, 1024, 0, stream>>>(bcur, bcurC, ebuf, cebuf, ecol, begN, endN, dis, N, CAP, CAPC);
        k_reduce  <<<(N + 3) / 4, 256, 0, stream>>>(begN, endN, ecol, dis, xlb, out, N);
    } else {
        // fallback: R1 atomic scatter path (fp32 xl)
        char* q = (char*)d_ws;
        float* xl   = (float*)q;
        float* disF = (float*)(q + (size_t)N * D * 4);
        int*   cc   = (int*)(q + (size_t)N * D * 4 + (size_t)N * 4);
        k_zero <<<gN, 256, 0, stream>>>(cc, N);
        k_deg  <<<gE, 256, 0, stream>>>(cols, cc, E);
        k_dis  <<<gN, 256, 0, stream>>>(cc, disF, N);
        k_gemmf<<<(N + GEMM_R - 1) / GEMM_R, 128, 0, stream>>>(x, W, b, xl, N);
        k_self <<<((N * D) + 255) / 256, 256, 0, stream>>>(xl, disF, out, N);
        long long st = (long long)E * 64;
        k_scatter<<<(int)((st + 255) / 256), 256, 0, stream>>>(rows, cols, disF, xl, out, E);
    }
}